// Round 8
// baseline (1673.571 us; speedup 1.0000x reference)
//
#include <hip/hip_runtime.h>

#define B_ 32
#define P_ 196
#define D_ 2048
#define A_ 512
#define E_ 512
#define H_ 512
#define V_ 10000
#define L_ 21
#define T_ 20
#define PP 208              /* padded P for encT rows (mult of 16) */

typedef unsigned short us;

struct KParams {
  const float* encoder_out; const int* captions; const int* cap_lens;
  const float* enc_att_w; const float* enc_att_b;
  const float* dec_att_w; const float* dec_att_b;
  const float* full_att_w; const float* full_att_b;
  const float* emb;
  const float* init_h_w; const float* init_h_b;
  const float* init_c_w; const float* init_c_b;
  const float* f_beta_w; const float* f_beta_b;
  const float* lstm_w_ih; const float* lstm_w_hh; const float* lstm_b;
  const float* fc_w; const float* fc_b;
  float* out_preds; float* out_caps; float* out_declens; float* out_alphas; float* out_sortind;
  int* sort_ind; int* declen; int* caps_s;
  us* h_bf16; float* c; us* mean_bf16;
  us* waw_bf16; us* wihE_bf16; us* embs_bf16;
  us* att1; us* Wt; us* Wt2; us* Wt3; us* encT; us* awe_bf16;
  float* gpre; float* s1out; float* alpha_g;
  int* sync;
};

__device__ __forceinline__ us f2bf(float x){
  unsigned u = __float_as_uint(x);
  unsigned r = ((u >> 16) & 1u) + 0x7FFFu;
  return (us)((u + r) >> 16);
}
__device__ __forceinline__ unsigned pack2(float a, float b){
  return (unsigned)f2bf(a) | ((unsigned)f2bf(b) << 16);
}
__device__ __forceinline__ float bf2f(unsigned u16){ return __uint_as_float(u16 << 16); }
__device__ __forceinline__ float sigm(float x){ return 1.f/(1.f + __expf(-x)); }
__device__ __forceinline__ float tanh_f(float x){ return 1.f - 2.f/(__expf(2.f*x) + 1.f); }

// Coherent (cross-XCD) 32-bit ops: bypass L1/L2, land at the device coherent point.
__device__ __forceinline__ unsigned ald(const unsigned* p){
  return __hip_atomic_load(p, __ATOMIC_RELAXED, __HIP_MEMORY_SCOPE_AGENT);
}
__device__ __forceinline__ void ast(unsigned* p, unsigned v){
  __hip_atomic_store(p, v, __ATOMIC_RELAXED, __HIP_MEMORY_SCOPE_AGENT);
}
__device__ __forceinline__ float aldf(const float* p){
  return __uint_as_float(ald((const unsigned*)p));
}
__device__ __forceinline__ void astf(float* p, float v){
  ast((unsigned*)p, __float_as_uint(v));
}

using bf16x8 = __attribute__((ext_vector_type(8))) short;
using f32x4  = __attribute__((ext_vector_type(4))) float;
#define MFMA(a,b,c) __builtin_amdgcn_mfma_f32_16x16x32_bf16((a),(b),(c),0,0,0)

// padded LDS strides (us units): row stride % 64us == 16 -> dword-stride % 32 == 8
// -> all 16 (row,lq) MFMA-fragment reads land on distinct banks (conflict-free).
#define HS 528     /* sm_h   row stride: 264 dw % 32 = 8 */
#define AS 2064    /* sm_awe row stride: 1032 dw % 32 = 8 */

// ---------------- prologue kernels ----------------

__global__ void k_meta(KParams p){
  __shared__ int len[32], sidx[32], sdecl[32];
  int tid = threadIdx.x;
  if (tid < 32) len[tid] = p.cap_lens[tid];
  __syncthreads();
  if (tid == 0){
    bool used[32];
    for (int i = 0; i < 32; i++) used[i] = false;
    for (int r = 0; r < 32; r++){
      int best = -1, bl = -2;
      for (int i = 0; i < 32; i++) if (!used[i] && len[i] > bl){ bl = len[i]; best = i; }
      used[best] = true; sidx[r] = best; sdecl[r] = bl - 1;
    }
  }
  __syncthreads();
  if (tid < 32){
    p.sort_ind[tid] = sidx[tid]; p.out_sortind[tid] = (float)sidx[tid];
    p.declen[tid]   = sdecl[tid]; p.out_declens[tid] = (float)sdecl[tid];
  }
  for (int idx = tid; idx < B_*L_; idx += 64){
    int b = idx / L_, l = idx - b*L_;
    int cv = p.captions[sidx[b]*L_ + l];
    p.caps_s[idx] = cv; p.out_caps[idx] = (float)cv;
  }
}

// 64x64 tile transpose: fp32 [R][C] -> bf16 [C][Rp], zero-pad rows >= R
__device__ void tp64(const float* src, us* dst, int R, int C, int Rp, int bi){
  __shared__ float tl[64][68];
  int tilesC = (C + 63) >> 6;
  int tr = bi / tilesC, tc = bi - tr*tilesC;
  int r0 = tr << 6, c0 = tc << 6;
  int tid = threadIdx.x;
  {
    int r = tid >> 2, cs = (tid & 3) << 4;
    bool rok = (r0 + r) < R;
    #pragma unroll
    for (int i = 0; i < 4; i++){
      int c = c0 + cs + i*4;
      float4 v = make_float4(0.f, 0.f, 0.f, 0.f);
      if (rok && c < C) v = *(const float4*)(src + (size_t)(r0 + r)*C + c);
      *(float4*)&tl[r][cs + i*4] = v;
    }
  }
  __syncthreads();
  {
    int c = tid >> 2, rs = (tid & 3) << 4;
    if (c0 + c < C && r0 + rs < Rp){
      us tmp[16];
      #pragma unroll
      for (int i = 0; i < 16; i++) tmp[i] = f2bf(tl[rs + i][c]);
      *(uint4*)(dst + (size_t)(c0 + c)*Rp + r0 + rs)     = *(uint4*)&tmp[0];
      *(uint4*)(dst + (size_t)(c0 + c)*Rp + r0 + rs + 8) = *(uint4*)&tmp[8];
    }
  }
}

__global__ void k_prep(KParams p){
  int bi = blockIdx.x, tid = threadIdx.x;
  if (bi < 512){                         // casts: enc_att_w, lstm_w_ih[:512]
    #pragma unroll
    for (int i = 0; i < 4; i++){
      int q = bi*1024 + i*256 + tid;
      const float4* src; uint2* dst; int qq;
      if (q < 262144){ src = (const float4*)p.enc_att_w; dst = (uint2*)p.waw_bf16;  qq = q; }
      else           { src = (const float4*)p.lstm_w_ih; dst = (uint2*)p.wihE_bf16; qq = q - 262144; }
      float4 v = src[qq];
      dst[qq] = make_uint2(pack2(v.x, v.y), pack2(v.z, v.w));
    }
  } else if (bi < 576){   tp64(p.dec_att_w, p.Wt,             512, 512,   512,  bi - 512);
  } else if (bi < 832){   tp64(p.f_beta_w,  p.Wt + 512*512,   512, 2048,  512,  bi - 576);
  } else if (bi < 1088){  tp64(p.lstm_w_hh, p.Wt + 2560*512,  512, 2048,  512,  bi - 832);
  } else if (bi < 2344){  tp64(p.fc_w,      p.Wt + 4608*512,  512, 10000, 512,  bi - 1088);
  } else if (bi < 3368){  tp64(p.lstm_w_ih + 512*2048, p.Wt2, 2048, 2048, 2048, bi - 2344);
  } else if (bi < 3624){  tp64(p.init_h_w,  p.Wt3,            2048, 512,  2048, bi - 3368);
  } else if (bi < 3880){  tp64(p.init_c_w,  p.Wt3 + 512*2048, 2048, 512,  2048, bi - 3624);
  } else if (bi < 4200){                 // embs gather -> bf16 [t][b][512]
    int q = (bi - 3880)*256 + tid;
    int row = q >> 7, qi = q & 127;
    int t = row >> 5, b = row & 31;
    int cap = p.caps_s[b*L_ + t];
    float4 v = ((const float4*)(p.emb + (size_t)cap*E_))[qi];
    ((uint2*)p.embs_bf16)[q] = make_uint2(pack2(v.x, v.y), pack2(v.z, v.w));
  } else {                               // encT: sorted enc [196][2048] -> [2048][208]
    int bl = bi - 4200;                  // 32*128
    int b = bl >> 7, ti = bl & 127;
    tp64(p.encoder_out + (size_t)p.sort_ind[b]*(P_*D_), p.encT + (size_t)b*D_*PP,
         196, 2048, PP, ti);
  }
}

// fused prologue GEMMs: bi<196 att1 (enc@enc_att_w, gathered fp32 A), else gpre (embs@wihE)
__global__ void __launch_bounds__(256) k_gemm2(KParams p){
  __shared__ us a_lds[128][40];
  __shared__ us b_lds[128][40];
  int bi = blockIdx.x;
  const us* Aq = nullptr; const float* Af = nullptr; const int* sidx = nullptr;
  const us* Bq; const float* bias; float* C; int N, K, obf, mode, ti;
  if (bi < 196){
    Af = p.encoder_out; sidx = p.sort_ind; Bq = p.waw_bf16; bias = p.enc_att_b;
    C = (float*)p.att1; N = 512; K = 2048; obf = 1; mode = 1; ti = bi;
  } else {
    Aq = p.embs_bf16; Bq = p.wihE_bf16; bias = p.lstm_b;
    C = p.gpre; N = 2048; K = 512; obf = 0; mode = 0; ti = bi - 196;
  }
  int ntiles = N >> 7;
  int bm = (ti / ntiles) << 7;
  int bn = (ti % ntiles) << 7;
  int tid = threadIdx.x;
  int wave = tid >> 6, lane = tid & 63;
  int wr = (wave >> 1) << 6, wc = (wave & 1) << 6;
  int la = lane & 15, lq = lane >> 4;
  f32x4 acc[4][4] = {};
  for (int k0 = 0; k0 < K; k0 += 32){
    {
      int r = tid >> 1, ch = (tid & 1) << 4;
      if (mode == 0){
        const uint4* asrc = (const uint4*)(Aq + (size_t)(bm + r)*K + k0 + ch);
        uint4 v0 = asrc[0], v1 = asrc[1];
        *(uint4*)&a_lds[r][ch]     = v0;
        *(uint4*)&a_lds[r][ch + 8] = v1;
      } else {
        int g = bm + r; int b = g / 196; int pp = g - b*196;
        const float4* as = (const float4*)(Af + ((size_t)sidx[b]*196 + pp)*2048 + k0 + ch);
        float4 f0 = as[0], f1 = as[1], f2 = as[2], f3 = as[3];
        *(uint4*)&a_lds[r][ch]     = make_uint4(pack2(f0.x,f0.y), pack2(f0.z,f0.w), pack2(f1.x,f1.y), pack2(f1.z,f1.w));
        *(uint4*)&a_lds[r][ch + 8] = make_uint4(pack2(f2.x,f2.y), pack2(f2.z,f2.w), pack2(f3.x,f3.y), pack2(f3.z,f3.w));
      }
      int kk = tid >> 3, n0 = (tid & 7) << 4;
      const us* bs = Bq + (size_t)(k0 + kk)*N + bn + n0;
      uint4 bv0 = *(const uint4*)bs, bv1 = *(const uint4*)(bs + 8);
      unsigned vals[8] = {bv0.x, bv0.y, bv0.z, bv0.w, bv1.x, bv1.y, bv1.z, bv1.w};
      #pragma unroll
      for (int i = 0; i < 8; i++){
        b_lds[n0 + 2*i][kk]     = (us)(vals[i] & 0xffffu);
        b_lds[n0 + 2*i + 1][kk] = (us)(vals[i] >> 16);
      }
    }
    __syncthreads();
    bf16x8 af[4], bfr[4];
    #pragma unroll
    for (int mt = 0; mt < 4; mt++) af[mt]  = *(const bf16x8*)&a_lds[wr + mt*16 + la][lq*8];
    #pragma unroll
    for (int nt = 0; nt < 4; nt++) bfr[nt] = *(const bf16x8*)&b_lds[wc + nt*16 + la][lq*8];
    #pragma unroll
    for (int mt = 0; mt < 4; mt++)
      #pragma unroll
      for (int nt = 0; nt < 4; nt++)
        acc[mt][nt] = MFMA(af[mt], bfr[nt], acc[mt][nt]);
    __syncthreads();
  }
  #pragma unroll
  for (int mt = 0; mt < 4; mt++){
    int row0 = bm + wr + mt*16 + lq*4;
    #pragma unroll
    for (int nt = 0; nt < 4; nt++){
      int coln = bn + wc + nt*16 + la;
      float bb = bias ? bias[coln] : 0.f;
      #pragma unroll
      for (int r = 0; r < 4; r++){
        float v = acc[mt][nt][r] + bb;
        if (obf) ((us*)C)[(size_t)(row0 + r)*N + coln] = f2bf(v);
        else     C[(size_t)(row0 + r)*N + coln] = v;
      }
    }
  }
}

// ---------------- cooperative scan kernel (8 groups x 32 blocks x 1024 threads) ----
// Round-8: round-7 structure (best: fence-free, 32-block jb-aligned groups,
// padded LDS) with 1024-thread blocks -> 16 waves/block = 4 waves/SIMD
// (VGPR<=128 via launch_bounds(1024,4)). Round 6->7 proved waves/SIMD is the
// lever (2x waves = -28% k_loop); this takes the remaining 2x without touching
// topology. Work spread to <=1 tile/wave: G1 = 288 s1out tiles + fc tiles 0..223
// in idle slots; G2 = attention (4 blocks) | fc tiles 224..624 at 1/wave;
// G4 = gate x K-quarter per wave.
// Barrier: 8 lines x 4 blocks -> master(8) -> flag; RELEASE adds, relaxed spins.

__device__ __forceinline__ void gsync_g(int* sc, int gen, int jb){
  __syncthreads();
  if (threadIdx.x == 0){
    int old = __hip_atomic_fetch_add(&sc[(jb & 7)*32], 1, __ATOMIC_RELEASE, __HIP_MEMORY_SCOPE_AGENT);
    bool last = false;
    if (old == gen*4 - 1){
      int old2 = __hip_atomic_fetch_add(&sc[512], 1, __ATOMIC_RELAXED, __HIP_MEMORY_SCOPE_AGENT);
      if (old2 == gen*8 - 1){
        __hip_atomic_store(&sc[544], gen, __ATOMIC_RELEASE, __HIP_MEMORY_SCOPE_AGENT);
        last = true;
      }
    }
    if (!last){
      while (__hip_atomic_load(&sc[544], __ATOMIC_RELAXED, __HIP_MEMORY_SCOPE_AGENT) < gen)
        __builtin_amdgcn_s_sleep(2);
    }
  }
  __syncthreads();
}

// fc over slots: M=16 tile with 4 valid rows (group batches), h from padded LDS stage
__device__ __forceinline__ void fc_run(const KParams& p, const int* sm_dl, const us* hlds,
                                       int b0, int slot, int nslots, int niter,
                                       int la, int lq, int tpred){
  bf16x8 afr[16];
  #pragma unroll
  for (int ks = 0; ks < 16; ks++) afr[ks] = *(const bf16x8*)&hlds[(la & 3)*HS + lq*8 + ks*32];
  for (int it = 0; it < niter; it++){
    int tile = slot + it*nslots;
    if (tile < 625){
      int n0 = tile*16;
      const us* wp = p.Wt + ((size_t)(4608 + n0 + la))*512 + lq*8;
      f32x4 ac = {};
      #pragma unroll
      for (int ks = 0; ks < 16; ks++){
        bf16x8 bB = *(const bf16x8*)(wp + ks*32);
        ac = MFMA(afr[ks], bB, ac);
      }
      if (lq == 0){
        int v = n0 + la;
        float bb = p.fc_b[v];
        #pragma unroll
        for (int r = 0; r < 4; r++){
          bool act = tpred < sm_dl[b0 + r];
          p.out_preds[((size_t)(b0 + r)*T_ + tpred)*V_ + v] = act ? (ac[r] + bb) : 0.f;
        }
      }
    }
  }
}

__global__ void __launch_bounds__(1024, 4) k_loop(KParams p){
  const int tid = threadIdx.x, blk = blockIdx.x;
  const int gb = blk >> 5, jb = blk & 31, b0 = gb*4;  // jb-aligned: XCD = jb%8 for all groups
  const int wv = tid >> 6, lane = tid & 63, la = lane & 15, lq = lane >> 4;
  int* sc = p.sync + gb*1024;
  __shared__ float sm_att2[512], sm_fw[512], sm_red[32];
  __shared__ float sm_a4f[4*PP];
  __shared__ float gq2[4][4][16][4];
  __shared__ int sm_dl[32];
  __shared__ us sm_h[4*HS];      // coherent-staged h rows (padded, conflict-free)
  __shared__ us sm_awe[4*AS];    // coherent-staged awe / mean (padded, conflict-free)
  int gen = 0;

  if (tid < 32) sm_dl[tid] = p.declen[tid];
  __syncthreads();

  // ===== GP1: mean over p — 64 d/block x 4 b, 4 threads per (d,b) =====
  {
    int part = tid & 3, pair = tid >> 2;
    int d = jb*64 + (pair >> 2), b = b0 + (pair & 3);
    const uint4* rp = (const uint4*)(p.encT + ((size_t)b*D_ + d)*PP);
    int cs = (part < 2) ? part*7 : 14 + (part - 2)*6;
    int ce = cs + ((part < 2) ? 7 : 6);
    float s = 0.f;
    for (int i = cs; i < ce; i++){
      uint4 u = rp[i];
      s += bf2f(u.x&0xffffu)+bf2f(u.x>>16)+bf2f(u.y&0xffffu)+bf2f(u.y>>16)
         + bf2f(u.z&0xffffu)+bf2f(u.z>>16)+bf2f(u.w&0xffffu)+bf2f(u.w>>16);
    }
    s += __shfl_xor(s, 1);
    s += __shfl_xor(s, 2);
    float mv = s*(1.f/196.f);
    float ov = __shfl_xor(mv, 16);          // partner: d^1 (tid bit4), same b
    if (part == 0 && !(tid & 16))
      ast((unsigned*)p.mean_bf16 + ((size_t)b*1024 + (d >> 1)), pack2(mv, ov));
  }
  gsync_g(sc, ++gen, jb);
  // ===== GP2: h0/c0 = mean @ Wt3 — 64 tiles over blocks 0..3 x 16 waves =====
  if (jb < 4){
    {
      unsigned* dst = (unsigned*)sm_awe;
      const unsigned* src = (const unsigned*)p.mean_bf16 + (size_t)b0*1024;
      for (int i = tid; i < 4096; i += 1024) dst[(i >> 10)*(AS >> 1) + (i & 1023)] = ald(src + i);
    }
    __syncthreads();
    int slot = jb*16 + wv;
    const us* wp = p.Wt3 + ((size_t)(slot*16 + la))*2048 + lq*8;
    const us* ap = sm_awe + (la & 3)*AS + lq*8;
    f32x4 ac0 = {}, ac1 = {};
    for (int ki = 0; ki < 64; ki += 2){
      bf16x8 aA = *(const bf16x8*)(ap + ki*32);
      bf16x8 bB = *(const bf16x8*)(wp + ki*32);
      ac0 = MFMA(aA, bB, ac0);
      bf16x8 aA2 = *(const bf16x8*)(ap + ki*32 + 32);
      bf16x8 bB2 = *(const bf16x8*)(wp + ki*32 + 32);
      ac1 = MFMA(aA2, bB2, ac1);
    }
    f32x4 ac = ac0 + ac1;
    int col = slot*16 + la;
    if (col < 512){
      #pragma unroll
      for (int r = 0; r < 4; r++){
        float v0 = ac[r] + p.init_h_b[col];
        float v1 = __shfl_xor(v0, 1);       // partner col^1, same r
        if (lq == 0 && !(la & 1))
          ast((unsigned*)p.h_bf16 + (((size_t)(b0+r)*512 + col) >> 1), pack2(v0, v1));
      }
    } else {
      #pragma unroll
      for (int r = 0; r < 4; r++)
        if (lq == 0) astf(&p.c[(size_t)(b0+r)*512 + col - 512], ac[r] + p.init_c_b[col - 512]);
    }
  }
  gsync_g(sc, ++gen, jb);

  for (int t = 0; t < T_; ++t){
    // ===== stage h (coherent) -> padded LDS; used by G1 s1out+fc, G2 fc =====
    {
      unsigned* dst = (unsigned*)sm_h;
      const unsigned* src = (const unsigned*)p.h_bf16 + (size_t)b0*256;
      for (int i = tid; i < 1024; i += 1024) dst[(i >> 8)*(HS >> 1) + (i & 255)] = ald(src + i);
    }
    __syncthreads();
    // ===== G1: 512 wave-slots: s1out tiles 0..287 | fc tiles 0..223 (preds t-1) =====
    {
      int slot = jb*16 + wv;
      if (slot < 288){
        bf16x8 afr[16];
        #pragma unroll
        for (int ks = 0; ks < 16; ks++) afr[ks] = *(const bf16x8*)&sm_h[(la & 3)*HS + lq*8 + ks*32];
        int n0 = slot*16;
        const us* wp = p.Wt + ((size_t)(n0 + la))*512 + lq*8;
        f32x4 ac = {};
        #pragma unroll
        for (int ks = 0; ks < 16; ks++){
          bf16x8 bB = *(const bf16x8*)(wp + ks*32);
          ac = MFMA(afr[ks], bB, ac);
        }
        if (lq == 0){
          #pragma unroll
          for (int r = 0; r < 4; r++) astf(&p.s1out[(size_t)(b0+r)*4608 + n0 + la], ac[r]);
        }
      } else if (t > 0){
        fc_run(p, sm_dl, sm_h, b0, slot - 288, 0, 1, la, lq, t - 1);
      }
    }
    gsync_g(sc, ++gen, jb);
    // ===== G2: blocks 0..3 attention softmax | blocks 4..31 fc tiles 224..624 =====
    if (jb < 4){
      int b = b0 + jb;
      for (int cc = tid; cc < 512; cc += 1024){
        sm_att2[cc] = aldf(&p.s1out[(size_t)b*4608 + cc]) + p.dec_att_b[cc];
        sm_fw[cc]   = p.full_att_w[cc];
      }
      __syncthreads();
      float ee = -1e30f;
      if (tid < 196){
        const uint4* row = (const uint4*)(p.att1 + ((size_t)(b*196 + tid))*512);
        float s = 0.f;
        #pragma unroll 8
        for (int i = 0; i < 64; i++){
          uint4 u = row[i];
          float4 a0 = *(const float4*)&sm_att2[i*8], a1 = *(const float4*)&sm_att2[i*8+4];
          float4 f0 = *(const float4*)&sm_fw[i*8],   f1 = *(const float4*)&sm_fw[i*8+4];
          s += fmaxf(bf2f(u.x&0xffffu)+a0.x,0.f)*f0.x + fmaxf(bf2f(u.x>>16)+a0.y,0.f)*f0.y
             + fmaxf(bf2f(u.y&0xffffu)+a0.z,0.f)*f0.z + fmaxf(bf2f(u.y>>16)+a0.w,0.f)*f0.w
             + fmaxf(bf2f(u.z&0xffffu)+a1.x,0.f)*f1.x + fmaxf(bf2f(u.z>>16)+a1.y,0.f)*f1.y
             + fmaxf(bf2f(u.w&0xffffu)+a1.z,0.f)*f1.z + fmaxf(bf2f(u.w>>16)+a1.w,0.f)*f1.w;
        }
        ee = s;
      }
      float v = ee;
      #pragma unroll
      for (int off = 32; off; off >>= 1) v = fmaxf(v, __shfl_xor(v, off));
      if (lane == 0) sm_red[wv] = v;
      __syncthreads();
      float m = sm_red[0];
      #pragma unroll
      for (int i = 1; i < 16; i++) m = fmaxf(m, sm_red[i]);
      float ex = (tid < 196) ? __expf(ee - m) : 0.f;
      float sv = ex;
      #pragma unroll
      for (int off = 32; off; off >>= 1) sv += __shfl_xor(sv, off);
      if (lane == 0) sm_red[16 + wv] = sv;
      __syncthreads();
      float ssum = sm_red[16];
      #pragma unroll
      for (int i = 1; i < 16; i++) ssum += sm_red[16 + i];
      if (tid < 196){
        float a = ex/ssum;
        astf(&p.alpha_g[b*PP + tid], a);
        bool act = t < sm_dl[b];
        p.out_alphas[((size_t)b*T_ + t)*P_ + tid] = act ? a : 0.f;
      } else if (tid < PP) astf(&p.alpha_g[b*PP + tid], 0.f);
    } else if (t > 0){
      fc_run(p, sm_dl, sm_h, b0, 224 + (jb - 4)*16 + wv, 0, 1, la, lq, t - 1);
    }
    gsync_g(sc, ++gen, jb);
    // ===== G3: awe = gate * (alpha @ enc) — 64 d/block x 4 b, 4 threads per (d,b) =====
    {
      for (int i = tid; i < 4*PP; i += 1024) sm_a4f[i] = aldf(&p.alpha_g[b0*PP + i]);
      __syncthreads();
      int part = tid & 3, pair = tid >> 2;
      int d = jb*64 + (pair >> 2), b = b0 + (pair & 3);
      const float* al = sm_a4f + (pair & 3)*PP;
      const uint4* rp = (const uint4*)(p.encT + ((size_t)b*D_ + d)*PP);
      int cs = (part < 2) ? part*7 : 14 + (part - 2)*6;
      int ce = cs + ((part < 2) ? 7 : 6);
      float acc = 0.f;
      for (int i = cs; i < ce; i++){
        uint4 u = rp[i];
        float4 a0 = *(const float4*)(al + i*8), a1 = *(const float4*)(al + i*8 + 4);
        acc += a0.x*bf2f(u.x&0xffffu) + a0.y*bf2f(u.x>>16)
             + a0.z*bf2f(u.y&0xffffu) + a0.w*bf2f(u.y>>16)
             + a1.x*bf2f(u.z&0xffffu) + a1.y*bf2f(u.z>>16)
             + a1.z*bf2f(u.w&0xffffu) + a1.w*bf2f(u.w>>16);
      }
      acc += __shfl_xor(acc, 1);
      acc += __shfl_xor(acc, 2);
      float gate = sigm(aldf(&p.s1out[(size_t)b*4608 + 512 + d]) + p.f_beta_b[d]);
      float wv_ = acc*gate;
      float ov = __shfl_xor(wv_, 16);       // partner: d^1 (tid bit4), same b
      if (part == 0 && !(tid & 16))
        ast((unsigned*)p.awe_bf16 + ((size_t)b*1024 + (d >> 1)), pack2(wv_, ov));
    }
    gsync_g(sc, ++gen, jb);
    // ===== G4: g = gpre + ghh + awe@Wt2 (gate x K-quarter per wave) + LSTM cell =====
    {
      {
        unsigned* dst = (unsigned*)sm_awe;
        const unsigned* src = (const unsigned*)p.awe_bf16 + (size_t)b0*1024;
        for (int i = tid; i < 4096; i += 1024) dst[(i >> 10)*(AS >> 1) + (i & 1023)] = ald(src + i);
      }
      __syncthreads();
      int q = wv >> 2, kh = wv & 3, hc0 = jb*16;
      const us* wp = p.Wt2 + ((size_t)(q*512 + hc0 + la))*2048 + kh*512 + lq*8;
      const us* ap = sm_awe + (la & 3)*AS + kh*512 + lq*8;
      f32x4 ac0 = {}, ac1 = {};
      for (int ki = 0; ki < 16; ki += 2){
        bf16x8 aA = *(const bf16x8*)(ap + ki*32);
        bf16x8 bB = *(const bf16x8*)(wp + ki*32);
        ac0 = MFMA(aA, bB, ac0);
        bf16x8 aA2 = *(const bf16x8*)(ap + ki*32 + 32);
        bf16x8 bB2 = *(const bf16x8*)(wp + ki*32 + 32);
        ac1 = MFMA(aA2, bB2, ac1);
      }
      f32x4 ac = ac0 + ac1;
      if (lq == 0){
        #pragma unroll
        for (int r = 0; r < 4; r++) gq2[q][kh][la][r] = ac[r];
      }
      __syncthreads();
      if (tid < 64){
        int hc = hc0 + (tid & 15), r = tid >> 4;
        int b = b0 + r;
        float gv[4];
        #pragma unroll
        for (int qq = 0; qq < 4; qq++)
          gv[qq] = gq2[qq][0][tid & 15][r] + gq2[qq][1][tid & 15][r]
                 + gq2[qq][2][tid & 15][r] + gq2[qq][3][tid & 15][r]
                 + aldf(&p.s1out[(size_t)b*4608 + 2560 + qq*512 + hc])
                 + p.gpre[((size_t)t*32 + b)*2048 + qq*512 + hc];
        float cold = aldf(&p.c[(size_t)b*512 + hc]);
        float cn = sigm(gv[1])*cold + sigm(gv[0])*tanh_f(gv[2]);
        float hn = sigm(gv[3])*tanh_f(cn);
        float hv1 = __shfl_xor(hn, 1);      // partner hc^1, same b
        if (t < sm_dl[b]){
          astf(&p.c[(size_t)b*512 + hc], cn);
          if (!(tid & 1))
            ast((unsigned*)p.h_bf16 + (((size_t)b*512 + hc) >> 1), pack2(hn, hv1));
        }
      }
    }
    gsync_g(sc, ++gen, jb);
  }
  // ===== epilogue: preds[T-1] (all 32 blocks x 16 waves per group) =====
  {
    unsigned* dst = (unsigned*)sm_h;
    const unsigned* src = (const unsigned*)p.h_bf16 + (size_t)b0*256;
    for (int i = tid; i < 1024; i += 1024) dst[(i >> 8)*(HS >> 1) + (i & 255)] = ald(src + i);
  }
  __syncthreads();
  fc_run(p, sm_dl, sm_h, b0, jb*16 + wv, 512, 2, la, lq, T_ - 1);
}

// ---------------- host launcher ----------------

extern "C" void kernel_launch(void* const* d_in, const int* in_sizes, int n_in,
                              void* d_out, int out_size, void* d_ws, size_t ws_size,
                              hipStream_t stream){
  (void)in_sizes; (void)n_in; (void)out_size; (void)ws_size;
  KParams p;
  p.encoder_out = (const float*)d_in[0];
  p.captions    = (const int*)d_in[1];
  p.cap_lens    = (const int*)d_in[2];
  p.enc_att_w   = (const float*)d_in[3];  p.enc_att_b = (const float*)d_in[4];
  p.dec_att_w   = (const float*)d_in[5];  p.dec_att_b = (const float*)d_in[6];
  p.full_att_w  = (const float*)d_in[7];  p.full_att_b = (const float*)d_in[8];
  p.emb         = (const float*)d_in[9];
  p.init_h_w    = (const float*)d_in[10]; p.init_h_b = (const float*)d_in[11];
  p.init_c_w    = (const float*)d_in[12]; p.init_c_b = (const float*)d_in[13];
  p.f_beta_w    = (const float*)d_in[14]; p.f_beta_b = (const float*)d_in[15];
  p.lstm_w_ih   = (const float*)d_in[16]; p.lstm_w_hh = (const float*)d_in[17]; p.lstm_b = (const float*)d_in[18];
  p.fc_w        = (const float*)d_in[19]; p.fc_b = (const float*)d_in[20];

  float* out = (float*)d_out;
  p.out_preds   = out;
  p.out_caps    = out + 6400000;
  p.out_declens = out + 6400672;
  p.out_alphas  = out + 6400704;
  p.out_sortind = out + 6526144;

  char* w = (char*)d_ws; size_t off = 0;
  auto alloc = [&](size_t bytes)->char*{ char* r = w + off; off = (off + bytes + 255) & ~(size_t)255; return r; };
  p.sort_ind  = (int*)alloc(128);
  p.declen    = (int*)alloc(128);
  p.caps_s    = (int*)alloc(2688);
  p.h_bf16    = (us*)alloc(32768);
  p.c         = (float*)alloc(65536);
  p.mean_bf16 = (us*)alloc(131072);
  p.waw_bf16  = (us*)alloc(2097152);
  p.wihE_bf16 = (us*)alloc(2097152);
  p.embs_bf16 = (us*)alloc(655360);
  p.att1      = (us*)alloc(6422528);     // [6272][512] bf16
  p.Wt        = (us*)alloc(14958592);    // [14608][512] bf16
  p.Wt2       = (us*)alloc(8388608);     // [2048][2048] bf16
  p.Wt3       = (us*)alloc(4194304);     // [1024][2048] bf16
  p.encT      = (us*)alloc(27262976);    // [32][2048][208] bf16
  p.gpre      = (float*)alloc(5242880);  // [20][32][2048]
  p.s1out     = (float*)alloc(589824);   // [32][4608]
  p.alpha_g   = (float*)alloc(26624);    // [32][208]
  p.awe_bf16  = (us*)alloc(131072);      // [32][2048]
  p.sync      = (int*)alloc(32768);      // 8 groups x 1024 ints

  hipMemsetAsync(p.sync, 0, 32768, stream);
  hipLaunchKernelGGL(k_meta,  dim3(1),    dim3(64),  0, stream, p);
  hipLaunchKernelGGL(k_prep,  dim3(8296), dim3(256), 0, stream, p);
  hipLaunchKernelGGL(k_gemm2, dim3(276),  dim3(256), 0, stream, p);
  void* args[] = { (void*)&p };
  hipLaunchCooperativeKernel((void*)k_loop, dim3(256), dim3(1024), args, 0, stream);
}

// Round 9
// 1660.303 us; speedup vs baseline: 1.0080x; 1.0080x over previous
//
#include <hip/hip_runtime.h>

#define B_ 32
#define P_ 196
#define D_ 2048
#define A_ 512
#define E_ 512
#define H_ 512
#define V_ 10000
#define L_ 21
#define T_ 20
#define PP 208              /* padded P for encT rows (mult of 16) */

typedef unsigned short us;

struct KParams {
  const float* encoder_out; const int* captions; const int* cap_lens;
  const float* enc_att_w; const float* enc_att_b;
  const float* dec_att_w; const float* dec_att_b;
  const float* full_att_w; const float* full_att_b;
  const float* emb;
  const float* init_h_w; const float* init_h_b;
  const float* init_c_w; const float* init_c_b;
  const float* f_beta_w; const float* f_beta_b;
  const float* lstm_w_ih; const float* lstm_w_hh; const float* lstm_b;
  const float* fc_w; const float* fc_b;
  float* out_preds; float* out_caps; float* out_declens; float* out_alphas; float* out_sortind;
  int* sort_ind; int* declen; int* caps_s;
  us* h_bf16; float* c; us* mean_bf16;
  us* waw_bf16; us* wihE_bf16; us* embs_bf16;
  us* att1; us* Wt; us* Wt2; us* Wt3; us* encT; us* awe_bf16;
  float* gpre; float* s1out; float* alpha_g;
  int* sync;
};

__device__ __forceinline__ us f2bf(float x){
  unsigned u = __float_as_uint(x);
  unsigned r = ((u >> 16) & 1u) + 0x7FFFu;
  return (us)((u + r) >> 16);
}
__device__ __forceinline__ unsigned pack2(float a, float b){
  return (unsigned)f2bf(a) | ((unsigned)f2bf(b) << 16);
}
__device__ __forceinline__ float bf2f(unsigned u16){ return __uint_as_float(u16 << 16); }
__device__ __forceinline__ float sigm(float x){ return 1.f/(1.f + __expf(-x)); }
__device__ __forceinline__ float tanh_f(float x){ return 1.f - 2.f/(__expf(2.f*x) + 1.f); }

// Coherent (cross-XCD) 32-bit ops: bypass L1/L2, land at the device coherent point.
__device__ __forceinline__ unsigned ald(const unsigned* p){
  return __hip_atomic_load(p, __ATOMIC_RELAXED, __HIP_MEMORY_SCOPE_AGENT);
}
__device__ __forceinline__ void ast(unsigned* p, unsigned v){
  __hip_atomic_store(p, v, __ATOMIC_RELAXED, __HIP_MEMORY_SCOPE_AGENT);
}
__device__ __forceinline__ float aldf(const float* p){
  return __uint_as_float(ald((const unsigned*)p));
}
__device__ __forceinline__ void astf(float* p, float v){
  ast((unsigned*)p, __float_as_uint(v));
}

using bf16x8 = __attribute__((ext_vector_type(8))) short;
using f32x4  = __attribute__((ext_vector_type(4))) float;
#define MFMA(a,b,c) __builtin_amdgcn_mfma_f32_16x16x32_bf16((a),(b),(c),0,0,0)

// padded LDS strides (us units): row stride % 64us == 16 -> dword-stride % 32 == 8
// -> all 16 (row,lq) MFMA-fragment reads land on distinct banks (conflict-free).
#define HS 528     /* sm_h   row stride: 264 dw % 32 = 8 */
#define AS 2064    /* sm_awe row stride: 1032 dw % 32 = 8 */

// ---------------- prologue kernels ----------------

__global__ void k_meta(KParams p){
  __shared__ int len[32], sidx[32], sdecl[32];
  int tid = threadIdx.x;
  if (tid < 32) len[tid] = p.cap_lens[tid];
  __syncthreads();
  if (tid == 0){
    bool used[32];
    for (int i = 0; i < 32; i++) used[i] = false;
    for (int r = 0; r < 32; r++){
      int best = -1, bl = -2;
      for (int i = 0; i < 32; i++) if (!used[i] && len[i] > bl){ bl = len[i]; best = i; }
      used[best] = true; sidx[r] = best; sdecl[r] = bl - 1;
    }
  }
  __syncthreads();
  if (tid < 32){
    p.sort_ind[tid] = sidx[tid]; p.out_sortind[tid] = (float)sidx[tid];
    p.declen[tid]   = sdecl[tid]; p.out_declens[tid] = (float)sdecl[tid];
  }
  for (int idx = tid; idx < B_*L_; idx += 64){
    int b = idx / L_, l = idx - b*L_;
    int cv = p.captions[sidx[b]*L_ + l];
    p.caps_s[idx] = cv; p.out_caps[idx] = (float)cv;
  }
}

// 64x64 tile transpose: fp32 [R][C] -> bf16 [C][Rp], zero-pad rows >= R
__device__ void tp64(const float* src, us* dst, int R, int C, int Rp, int bi){
  __shared__ float tl[64][68];
  int tilesC = (C + 63) >> 6;
  int tr = bi / tilesC, tc = bi - tr*tilesC;
  int r0 = tr << 6, c0 = tc << 6;
  int tid = threadIdx.x;
  {
    int r = tid >> 2, cs = (tid & 3) << 4;
    bool rok = (r0 + r) < R;
    #pragma unroll
    for (int i = 0; i < 4; i++){
      int c = c0 + cs + i*4;
      float4 v = make_float4(0.f, 0.f, 0.f, 0.f);
      if (rok && c < C) v = *(const float4*)(src + (size_t)(r0 + r)*C + c);
      *(float4*)&tl[r][cs + i*4] = v;
    }
  }
  __syncthreads();
  {
    int c = tid >> 2, rs = (tid & 3) << 4;
    if (c0 + c < C && r0 + rs < Rp){
      us tmp[16];
      #pragma unroll
      for (int i = 0; i < 16; i++) tmp[i] = f2bf(tl[rs + i][c]);
      *(uint4*)(dst + (size_t)(c0 + c)*Rp + r0 + rs)     = *(uint4*)&tmp[0];
      *(uint4*)(dst + (size_t)(c0 + c)*Rp + r0 + rs + 8) = *(uint4*)&tmp[8];
    }
  }
}

__global__ void k_prep(KParams p){
  int bi = blockIdx.x, tid = threadIdx.x;
  if (bi < 512){                         // casts: enc_att_w, lstm_w_ih[:512]
    #pragma unroll
    for (int i = 0; i < 4; i++){
      int q = bi*1024 + i*256 + tid;
      const float4* src; uint2* dst; int qq;
      if (q < 262144){ src = (const float4*)p.enc_att_w; dst = (uint2*)p.waw_bf16;  qq = q; }
      else           { src = (const float4*)p.lstm_w_ih; dst = (uint2*)p.wihE_bf16; qq = q - 262144; }
      float4 v = src[qq];
      dst[qq] = make_uint2(pack2(v.x, v.y), pack2(v.z, v.w));
    }
  } else if (bi < 576){   tp64(p.dec_att_w, p.Wt,             512, 512,   512,  bi - 512);
  } else if (bi < 832){   tp64(p.f_beta_w,  p.Wt + 512*512,   512, 2048,  512,  bi - 576);
  } else if (bi < 1088){  tp64(p.lstm_w_hh, p.Wt + 2560*512,  512, 2048,  512,  bi - 832);
  } else if (bi < 2344){  tp64(p.fc_w,      p.Wt + 4608*512,  512, 10000, 512,  bi - 1088);
  } else if (bi < 3368){  tp64(p.lstm_w_ih + 512*2048, p.Wt2, 2048, 2048, 2048, bi - 2344);
  } else if (bi < 3624){  tp64(p.init_h_w,  p.Wt3,            2048, 512,  2048, bi - 3368);
  } else if (bi < 3880){  tp64(p.init_c_w,  p.Wt3 + 512*2048, 2048, 512,  2048, bi - 3624);
  } else if (bi < 4200){                 // embs gather -> bf16 [t][b][512]
    int q = (bi - 3880)*256 + tid;
    int row = q >> 7, qi = q & 127;
    int t = row >> 5, b = row & 31;
    int cap = p.caps_s[b*L_ + t];
    float4 v = ((const float4*)(p.emb + (size_t)cap*E_))[qi];
    ((uint2*)p.embs_bf16)[q] = make_uint2(pack2(v.x, v.y), pack2(v.z, v.w));
  } else {                               // encT: sorted enc [196][2048] -> [2048][208]
    int bl = bi - 4200;                  // 32*128
    int b = bl >> 7, ti = bl & 127;
    tp64(p.encoder_out + (size_t)p.sort_ind[b]*(P_*D_), p.encT + (size_t)b*D_*PP,
         196, 2048, PP, ti);
  }
}

// fused prologue GEMMs: bi<196 att1 (enc@enc_att_w, gathered fp32 A), else gpre (embs@wihE)
__global__ void __launch_bounds__(256) k_gemm2(KParams p){
  __shared__ us a_lds[128][40];
  __shared__ us b_lds[128][40];
  int bi = blockIdx.x;
  const us* Aq = nullptr; const float* Af = nullptr; const int* sidx = nullptr;
  const us* Bq; const float* bias; float* C; int N, K, obf, mode, ti;
  if (bi < 196){
    Af = p.encoder_out; sidx = p.sort_ind; Bq = p.waw_bf16; bias = p.enc_att_b;
    C = (float*)p.att1; N = 512; K = 2048; obf = 1; mode = 1; ti = bi;
  } else {
    Aq = p.embs_bf16; Bq = p.wihE_bf16; bias = p.lstm_b;
    C = p.gpre; N = 2048; K = 512; obf = 0; mode = 0; ti = bi - 196;
  }
  int ntiles = N >> 7;
  int bm = (ti / ntiles) << 7;
  int bn = (ti % ntiles) << 7;
  int tid = threadIdx.x;
  int wave = tid >> 6, lane = tid & 63;
  int wr = (wave >> 1) << 6, wc = (wave & 1) << 6;
  int la = lane & 15, lq = lane >> 4;
  f32x4 acc[4][4] = {};
  for (int k0 = 0; k0 < K; k0 += 32){
    {
      int r = tid >> 1, ch = (tid & 1) << 4;
      if (mode == 0){
        const uint4* asrc = (const uint4*)(Aq + (size_t)(bm + r)*K + k0 + ch);
        uint4 v0 = asrc[0], v1 = asrc[1];
        *(uint4*)&a_lds[r][ch]     = v0;
        *(uint4*)&a_lds[r][ch + 8] = v1;
      } else {
        int g = bm + r; int b = g / 196; int pp = g - b*196;
        const float4* as = (const float4*)(Af + ((size_t)sidx[b]*196 + pp)*2048 + k0 + ch);
        float4 f0 = as[0], f1 = as[1], f2 = as[2], f3 = as[3];
        *(uint4*)&a_lds[r][ch]     = make_uint4(pack2(f0.x,f0.y), pack2(f0.z,f0.w), pack2(f1.x,f1.y), pack2(f1.z,f1.w));
        *(uint4*)&a_lds[r][ch + 8] = make_uint4(pack2(f2.x,f2.y), pack2(f2.z,f2.w), pack2(f3.x,f3.y), pack2(f3.z,f3.w));
      }
      int kk = tid >> 3, n0 = (tid & 7) << 4;
      const us* bs = Bq + (size_t)(k0 + kk)*N + bn + n0;
      uint4 bv0 = *(const uint4*)bs, bv1 = *(const uint4*)(bs + 8);
      unsigned vals[8] = {bv0.x, bv0.y, bv0.z, bv0.w, bv1.x, bv1.y, bv1.z, bv1.w};
      #pragma unroll
      for (int i = 0; i < 8; i++){
        b_lds[n0 + 2*i][kk]     = (us)(vals[i] & 0xffffu);
        b_lds[n0 + 2*i + 1][kk] = (us)(vals[i] >> 16);
      }
    }
    __syncthreads();
    bf16x8 af[4], bfr[4];
    #pragma unroll
    for (int mt = 0; mt < 4; mt++) af[mt]  = *(const bf16x8*)&a_lds[wr + mt*16 + la][lq*8];
    #pragma unroll
    for (int nt = 0; nt < 4; nt++) bfr[nt] = *(const bf16x8*)&b_lds[wc + nt*16 + la][lq*8];
    #pragma unroll
    for (int mt = 0; mt < 4; mt++)
      #pragma unroll
      for (int nt = 0; nt < 4; nt++)
        acc[mt][nt] = MFMA(af[mt], bfr[nt], acc[mt][nt]);
    __syncthreads();
  }
  #pragma unroll
  for (int mt = 0; mt < 4; mt++){
    int row0 = bm + wr + mt*16 + lq*4;
    #pragma unroll
    for (int nt = 0; nt < 4; nt++){
      int coln = bn + wc + nt*16 + la;
      float bb = bias ? bias[coln] : 0.f;
      #pragma unroll
      for (int r = 0; r < 4; r++){
        float v = acc[mt][nt][r] + bb;
        if (obf) ((us*)C)[(size_t)(row0 + r)*N + coln] = f2bf(v);
        else     C[(size_t)(row0 + r)*N + coln] = v;
      }
    }
  }
}

// ---------------- cooperative scan kernel (8 groups x 32 blocks x 512 threads) ----
// Round-9: round-7 compute structure (best measured: fence-free, 32-block
// jb-aligned groups, 512-thread blocks = 2 waves/SIMD, padded LDS) with the
// barrier term attacked on both factors (r6/r7 fit: barrier+serial ~37us/step):
//  (1) COUNT: G1 fused into G2. Attention blocks (jb<4) compute their own att2
//      slice redundantly (32 tiles, keep batch-row jb); s1out cols 0..511 are
//      consumed only by attention, so the global pass covers tiles 32..287 and
//      is merged with all 625 fc tiles into one 881-job pool over the 224
//      non-attention wave-slots. 3 barriers/step instead of 4 (82 -> 62 total).
//  (2) LATENCY: single per-group counter barrier - arrival fetch_add(RELEASE),
//      spin until count >= gen*32. Removes the line->master->flag chain
//      (2 coherent-point round-trips) and the s_sleep poll granularity.
// Topology: gb=blk>>5, jb=blk&31 -> XCD = jb%8 for all groups; weight tiles are
// pure functions of (jb,wv) -> 8-way cross-group L2 sharing per XCD.

__device__ __forceinline__ void gsync_g(int* sc, int gen){
  __syncthreads();
  if (threadIdx.x == 0){
    __hip_atomic_fetch_add(&sc[0], 1, __ATOMIC_RELEASE, __HIP_MEMORY_SCOPE_AGENT);
    while (__hip_atomic_load(&sc[0], __ATOMIC_RELAXED, __HIP_MEMORY_SCOPE_AGENT) < gen*32) {}
  }
  __syncthreads();
}

// fc over slots: M=16 tile with 4 valid rows (group batches), h from padded LDS stage
__device__ __forceinline__ void fc_run(const KParams& p, const int* sm_dl, const us* hlds,
                                       int b0, int slot, int nslots, int niter,
                                       int la, int lq, int tpred){
  bf16x8 afr[16];
  #pragma unroll
  for (int ks = 0; ks < 16; ks++) afr[ks] = *(const bf16x8*)&hlds[(la & 3)*HS + lq*8 + ks*32];
  for (int it = 0; it < niter; it++){
    int tile = slot + it*nslots;
    if (tile < 625){
      int n0 = tile*16;
      const us* wp = p.Wt + ((size_t)(4608 + n0 + la))*512 + lq*8;
      f32x4 ac = {};
      #pragma unroll
      for (int ks = 0; ks < 16; ks++){
        bf16x8 bB = *(const bf16x8*)(wp + ks*32);
        ac = MFMA(afr[ks], bB, ac);
      }
      if (lq == 0){
        int v = n0 + la;
        float bb = p.fc_b[v];
        #pragma unroll
        for (int r = 0; r < 4; r++){
          bool act = tpred < sm_dl[b0 + r];
          p.out_preds[((size_t)(b0 + r)*T_ + tpred)*V_ + v] = act ? (ac[r] + bb) : 0.f;
        }
      }
    }
  }
}

__global__ void __launch_bounds__(512, 2) k_loop(KParams p){
  const int tid = threadIdx.x, blk = blockIdx.x;
  const int gb = blk >> 5, jb = blk & 31, b0 = gb*4;  // jb-aligned: XCD = jb%8 for all groups
  const int wv = tid >> 6, lane = tid & 63, la = lane & 15, lq = lane >> 4;
  int* sc = p.sync + gb*1024;
  __shared__ float sm_att2[512], sm_fw[512], sm_red[16];
  __shared__ float sm_a4f[4*PP];
  __shared__ float gq2[4][2][16][4];
  __shared__ int sm_dl[32];
  __shared__ us sm_h[4*HS];      // coherent-staged h rows (padded, conflict-free)
  __shared__ us sm_awe[4*AS];    // coherent-staged awe / mean (padded, conflict-free)
  int gen = 0;

  if (tid < 32) sm_dl[tid] = p.declen[tid];
  __syncthreads();

  // ===== GP1: mean over p — 64 d/block x 4 b, 2 threads per (d,b) =====
  {
    int part = tid & 1, pair = tid >> 1;
    int d = jb*64 + (pair >> 2), b = b0 + (pair & 3);
    const uint4* rp = (const uint4*)(p.encT + ((size_t)b*D_ + d)*PP);
    int cs = part*13;
    float s = 0.f;
    for (int i = cs; i < cs + 13; i++){
      uint4 u = rp[i];
      s += bf2f(u.x&0xffffu)+bf2f(u.x>>16)+bf2f(u.y&0xffffu)+bf2f(u.y>>16)
         + bf2f(u.z&0xffffu)+bf2f(u.z>>16)+bf2f(u.w&0xffffu)+bf2f(u.w>>16);
    }
    s += __shfl_xor(s, 1);
    float mv = s*(1.f/196.f);
    float ov = __shfl_xor(mv, 8);           // partner: d^1 (tid bit3), same b
    if (part == 0 && !(tid & 8))
      ast((unsigned*)p.mean_bf16 + ((size_t)b*1024 + (d >> 1)), pack2(mv, ov));
  }
  gsync_g(sc, ++gen);
  // ===== GP2: h0/c0 = mean @ Wt3 — 64 tiles over blocks 0..7 x 8 waves =====
  if (jb < 8){
    {
      unsigned* dst = (unsigned*)sm_awe;
      const unsigned* src = (const unsigned*)p.mean_bf16 + (size_t)b0*1024;
      for (int i = tid; i < 4096; i += 512) dst[(i >> 10)*(AS >> 1) + (i & 1023)] = ald(src + i);
    }
    __syncthreads();
    int slot = jb*8 + wv;
    const us* wp = p.Wt3 + ((size_t)(slot*16 + la))*2048 + lq*8;
    const us* ap = sm_awe + (la & 3)*AS + lq*8;
    f32x4 ac0 = {}, ac1 = {};
    for (int ki = 0; ki < 64; ki += 2){
      bf16x8 aA = *(const bf16x8*)(ap + ki*32);
      bf16x8 bB = *(const bf16x8*)(wp + ki*32);
      ac0 = MFMA(aA, bB, ac0);
      bf16x8 aA2 = *(const bf16x8*)(ap + ki*32 + 32);
      bf16x8 bB2 = *(const bf16x8*)(wp + ki*32 + 32);
      ac1 = MFMA(aA2, bB2, ac1);
    }
    f32x4 ac = ac0 + ac1;
    int col = slot*16 + la;
    if (col < 512){
      #pragma unroll
      for (int r = 0; r < 4; r++){
        float v0 = ac[r] + p.init_h_b[col];
        float v1 = __shfl_xor(v0, 1);       // partner col^1, same r
        if (lq == 0 && !(la & 1))
          ast((unsigned*)p.h_bf16 + (((size_t)(b0+r)*512 + col) >> 1), pack2(v0, v1));
      }
    } else {
      #pragma unroll
      for (int r = 0; r < 4; r++)
        if (lq == 0) astf(&p.c[(size_t)(b0+r)*512 + col - 512], ac[r] + p.init_c_b[col - 512]);
    }
  }
  gsync_g(sc, ++gen);

  for (int t = 0; t < T_; ++t){
    // ===== stage h (coherent) -> padded LDS =====
    {
      unsigned* dst = (unsigned*)sm_h;
      const unsigned* src = (const unsigned*)p.h_bf16 + (size_t)b0*256;
      for (int i = tid; i < 1024; i += 512) dst[(i >> 8)*(HS >> 1) + (i & 255)] = ald(src + i);
    }
    __syncthreads();
    // ===== Phase A (fused G1+G2) =====
    // h-fragments, shared by both branches
    bf16x8 afr[16];
    #pragma unroll
    for (int ks = 0; ks < 16; ks++) afr[ks] = *(const bf16x8*)&sm_h[(la & 3)*HS + lq*8 + ks*32];
    if (jb < 4){
      // attention block: redundant att2 (32 tiles, keep batch-row jb) + softmax
      int b = b0 + jb;
      for (int cc = tid; cc < 512; cc += 512) sm_fw[cc] = p.full_att_w[cc];
      #pragma unroll
      for (int tt = 0; tt < 4; tt++){
        int n0 = (wv*4 + tt)*16;
        const us* wp = p.Wt + ((size_t)(n0 + la))*512 + lq*8;
        f32x4 ac = {};
        #pragma unroll
        for (int ks = 0; ks < 16; ks++){
          bf16x8 bB = *(const bf16x8*)(wp + ks*32);
          ac = MFMA(afr[ks], bB, ac);
        }
        if (lq == 0) sm_att2[n0 + la] = ac[jb] + p.dec_att_b[n0 + la];
      }
      __syncthreads();
      float ee = -1e30f;
      if (tid < 196){
        const uint4* row = (const uint4*)(p.att1 + ((size_t)(b*196 + tid))*512);
        float s = 0.f;
        #pragma unroll 8
        for (int i = 0; i < 64; i++){
          uint4 u = row[i];
          float4 a0 = *(const float4*)&sm_att2[i*8], a1 = *(const float4*)&sm_att2[i*8+4];
          float4 f0 = *(const float4*)&sm_fw[i*8],   f1 = *(const float4*)&sm_fw[i*8+4];
          s += fmaxf(bf2f(u.x&0xffffu)+a0.x,0.f)*f0.x + fmaxf(bf2f(u.x>>16)+a0.y,0.f)*f0.y
             + fmaxf(bf2f(u.y&0xffffu)+a0.z,0.f)*f0.z + fmaxf(bf2f(u.y>>16)+a0.w,0.f)*f0.w
             + fmaxf(bf2f(u.z&0xffffu)+a1.x,0.f)*f1.x + fmaxf(bf2f(u.z>>16)+a1.y,0.f)*f1.y
             + fmaxf(bf2f(u.w&0xffffu)+a1.z,0.f)*f1.z + fmaxf(bf2f(u.w>>16)+a1.w,0.f)*f1.w;
        }
        ee = s;
      }
      float v = ee;
      #pragma unroll
      for (int off = 32; off; off >>= 1) v = fmaxf(v, __shfl_xor(v, off));
      if (lane == 0) sm_red[wv] = v;
      __syncthreads();
      float m = sm_red[0];
      #pragma unroll
      for (int i = 1; i < 8; i++) m = fmaxf(m, sm_red[i]);
      float ex = (tid < 196) ? __expf(ee - m) : 0.f;
      float sv = ex;
      #pragma unroll
      for (int off = 32; off; off >>= 1) sv += __shfl_xor(sv, off);
      if (lane == 0) sm_red[8 + wv] = sv;
      __syncthreads();
      float ssum = sm_red[8];
      #pragma unroll
      for (int i = 1; i < 8; i++) ssum += sm_red[8 + i];
      if (tid < 196){
        float a = ex/ssum;
        astf(&p.alpha_g[b*PP + tid], a);
        bool act = t < sm_dl[b];
        p.out_alphas[((size_t)b*T_ + t)*P_ + tid] = act ? a : 0.f;
      } else if (tid < PP) astf(&p.alpha_g[b*PP + tid], 0.f);
    } else {
      // 881 jobs (256 s1out tiles 32..287, then 625 fc tiles) over 224 slots
      int slot = (jb - 4)*8 + wv;
      #pragma unroll
      for (int it = 0; it < 4; it++){
        int j = slot + it*224;
        if (j < 881){
          bool isfc = (j >= 256);
          if (!isfc || t > 0){
            int row0 = isfc ? (4608 + (j - 256)*16) : ((32 + j)*16);
            const us* wp = p.Wt + ((size_t)(row0 + la))*512 + lq*8;
            f32x4 ac = {};
            #pragma unroll
            for (int ks = 0; ks < 16; ks++){
              bf16x8 bB = *(const bf16x8*)(wp + ks*32);
              ac = MFMA(afr[ks], bB, ac);
            }
            if (lq == 0){
              if (!isfc){
                #pragma unroll
                for (int r = 0; r < 4; r++) astf(&p.s1out[(size_t)(b0+r)*4608 + row0 + la], ac[r]);
              } else {
                int vv = row0 - 4608 + la;
                float bb = p.fc_b[vv];
                #pragma unroll
                for (int r = 0; r < 4; r++){
                  bool act = (t - 1) < sm_dl[b0 + r];
                  p.out_preds[((size_t)(b0 + r)*T_ + (t - 1))*V_ + vv] = act ? (ac[r] + bb) : 0.f;
                }
              }
            }
          }
        }
      }
    }
    gsync_g(sc, ++gen);
    // ===== Phase B: awe = gate * (alpha @ enc) — 64 d/block x 4 b, 2 thr/(d,b) =====
    {
      for (int i = tid; i < 4*PP; i += 512) sm_a4f[i] = aldf(&p.alpha_g[b0*PP + i]);
      __syncthreads();
      int part = tid & 1, pair = tid >> 1;
      int d = jb*64 + (pair >> 2), b = b0 + (pair & 3);
      const float* al = sm_a4f + (pair & 3)*PP;
      const uint4* rp = (const uint4*)(p.encT + ((size_t)b*D_ + d)*PP);
      int cs = part*13;
      float acc = 0.f;
      for (int i = cs; i < cs + 13; i++){
        uint4 u = rp[i];
        float4 a0 = *(const float4*)(al + i*8), a1 = *(const float4*)(al + i*8 + 4);
        acc += a0.x*bf2f(u.x&0xffffu) + a0.y*bf2f(u.x>>16)
             + a0.z*bf2f(u.y&0xffffu) + a0.w*bf2f(u.y>>16)
             + a1.x*bf2f(u.z&0xffffu) + a1.y*bf2f(u.z>>16)
             + a1.z*bf2f(u.w&0xffffu) + a1.w*bf2f(u.w>>16);
      }
      acc += __shfl_xor(acc, 1);
      float gate = sigm(aldf(&p.s1out[(size_t)b*4608 + 512 + d]) + p.f_beta_b[d]);
      float wv_ = acc*gate;
      float ov = __shfl_xor(wv_, 8);        // partner: d^1 (tid bit3), same b
      if (part == 0 && !(tid & 8))
        ast((unsigned*)p.awe_bf16 + ((size_t)b*1024 + (d >> 1)), pack2(wv_, ov));
    }
    gsync_g(sc, ++gen);
    // ===== Phase C: g = gpre + ghh + awe@Wt2 (gate x K-half per wave) + LSTM =====
    {
      {
        unsigned* dst = (unsigned*)sm_awe;
        const unsigned* src = (const unsigned*)p.awe_bf16 + (size_t)b0*1024;
        for (int i = tid; i < 4096; i += 512) dst[(i >> 10)*(AS >> 1) + (i & 1023)] = ald(src + i);
      }
      __syncthreads();
      int q = wv >> 1, kh = wv & 1, hc0 = jb*16;
      const us* wp = p.Wt2 + ((size_t)(q*512 + hc0 + la))*2048 + kh*1024 + lq*8;
      const us* ap = sm_awe + (la & 3)*AS + kh*1024 + lq*8;
      f32x4 ac0 = {}, ac1 = {};
      for (int ki = 0; ki < 32; ki += 2){
        bf16x8 aA = *(const bf16x8*)(ap + ki*32);
        bf16x8 bB = *(const bf16x8*)(wp + ki*32);
        ac0 = MFMA(aA, bB, ac0);
        bf16x8 aA2 = *(const bf16x8*)(ap + ki*32 + 32);
        bf16x8 bB2 = *(const bf16x8*)(wp + ki*32 + 32);
        ac1 = MFMA(aA2, bB2, ac1);
      }
      f32x4 ac = ac0 + ac1;
      if (lq == 0){
        #pragma unroll
        for (int r = 0; r < 4; r++) gq2[q][kh][la][r] = ac[r];
      }
      __syncthreads();
      if (tid < 64){
        int hc = hc0 + (tid & 15), r = tid >> 4;
        int b = b0 + r;
        float gv[4];
        #pragma unroll
        for (int qq = 0; qq < 4; qq++)
          gv[qq] = gq2[qq][0][tid & 15][r] + gq2[qq][1][tid & 15][r]
                 + aldf(&p.s1out[(size_t)b*4608 + 2560 + qq*512 + hc])
                 + p.gpre[((size_t)t*32 + b)*2048 + qq*512 + hc];
        float cold = aldf(&p.c[(size_t)b*512 + hc]);
        float cn = sigm(gv[1])*cold + sigm(gv[0])*tanh_f(gv[2]);
        float hn = sigm(gv[3])*tanh_f(cn);
        float hv1 = __shfl_xor(hn, 1);      // partner hc^1, same b
        if (t < sm_dl[b]){
          astf(&p.c[(size_t)b*512 + hc], cn);
          if (!(tid & 1))
            ast((unsigned*)p.h_bf16 + (((size_t)b*512 + hc) >> 1), pack2(hn, hv1));
        }
      }
    }
    gsync_g(sc, ++gen);
  }
  // ===== epilogue: preds[T-1] (all 32 blocks x 8 waves per group) =====
  {
    unsigned* dst = (unsigned*)sm_h;
    const unsigned* src = (const unsigned*)p.h_bf16 + (size_t)b0*256;
    for (int i = tid; i < 1024; i += 512) dst[(i >> 8)*(HS >> 1) + (i & 255)] = ald(src + i);
  }
  __syncthreads();
  fc_run(p, sm_dl, sm_h, b0, jb*8 + wv, 256, 3, la, lq, T_ - 1);
}

// ---------------- host launcher ----------------

extern "C" void kernel_launch(void* const* d_in, const int* in_sizes, int n_in,
                              void* d_out, int out_size, void* d_ws, size_t ws_size,
                              hipStream_t stream){
  (void)in_sizes; (void)n_in; (void)out_size; (void)ws_size;
  KParams p;
  p.encoder_out = (const float*)d_in[0];
  p.captions    = (const int*)d_in[1];
  p.cap_lens    = (const int*)d_in[2];
  p.enc_att_w   = (const float*)d_in[3];  p.enc_att_b = (const float*)d_in[4];
  p.dec_att_w   = (const float*)d_in[5];  p.dec_att_b = (const float*)d_in[6];
  p.full_att_w  = (const float*)d_in[7];  p.full_att_b = (const float*)d_in[8];
  p.emb         = (const float*)d_in[9];
  p.init_h_w    = (const float*)d_in[10]; p.init_h_b = (const float*)d_in[11];
  p.init_c_w    = (const float*)d_in[12]; p.init_c_b = (const float*)d_in[13];
  p.f_beta_w    = (const float*)d_in[14]; p.f_beta_b = (const float*)d_in[15];
  p.lstm_w_ih   = (const float*)d_in[16]; p.lstm_w_hh = (const float*)d_in[17]; p.lstm_b = (const float*)d_in[18];
  p.fc_w        = (const float*)d_in[19]; p.fc_b = (const float*)d_in[20];

  float* out = (float*)d_out;
  p.out_preds   = out;
  p.out_caps    = out + 6400000;
  p.out_declens = out + 6400672;
  p.out_alphas  = out + 6400704;
  p.out_sortind = out + 6526144;

  char* w = (char*)d_ws; size_t off = 0;
  auto alloc = [&](size_t bytes)->char*{ char* r = w + off; off = (off + bytes + 255) & ~(size_t)255; return r; };
  p.sort_ind  = (int*)alloc(128);
  p.declen    = (int*)alloc(128);
  p.caps_s    = (int*)alloc(2688);
  p.h_bf16    = (us*)alloc(32768);
  p.c         = (float*)alloc(65536);
  p.mean_bf16 = (us*)alloc(131072);
  p.waw_bf16  = (us*)alloc(2097152);
  p.wihE_bf16 = (us*)alloc(2097152);
  p.embs_bf16 = (us*)alloc(655360);
  p.att1      = (us*)alloc(6422528);     // [6272][512] bf16
  p.Wt        = (us*)alloc(14958592);    // [14608][512] bf16
  p.Wt2       = (us*)alloc(8388608);     // [2048][2048] bf16
  p.Wt3       = (us*)alloc(4194304);     // [1024][2048] bf16
  p.encT      = (us*)alloc(27262976);    // [32][2048][208] bf16
  p.gpre      = (float*)alloc(5242880);  // [20][32][2048]
  p.s1out     = (float*)alloc(589824);   // [32][4608]
  p.alpha_g   = (float*)alloc(26624);    // [32][208]
  p.awe_bf16  = (us*)alloc(131072);      // [32][2048]
  p.sync      = (int*)alloc(32768);      // 8 groups x 1024 ints

  hipMemsetAsync(p.sync, 0, 32768, stream);
  hipLaunchKernelGGL(k_meta,  dim3(1),    dim3(64),  0, stream, p);
  hipLaunchKernelGGL(k_prep,  dim3(8296), dim3(256), 0, stream, p);
  hipLaunchKernelGGL(k_gemm2, dim3(276),  dim3(256), 0, stream, p);
  void* args[] = { (void*)&p };
  hipLaunchCooperativeKernel((void*)k_loop, dim3(256), dim3(512), args, 0, stream);
}

// Round 10
// 1559.226 us; speedup vs baseline: 1.0733x; 1.0648x over previous
//
#include <hip/hip_runtime.h>

#define B_ 32
#define P_ 196
#define D_ 2048
#define A_ 512
#define E_ 512
#define H_ 512
#define V_ 10000
#define L_ 21
#define T_ 20
#define PP 208              /* padded P for encT rows (mult of 16) */

typedef unsigned short us;

struct KParams {
  const float* encoder_out; const int* captions; const int* cap_lens;
  const float* enc_att_w; const float* enc_att_b;
  const float* dec_att_w; const float* dec_att_b;
  const float* full_att_w; const float* full_att_b;
  const float* emb;
  const float* init_h_w; const float* init_h_b;
  const float* init_c_w; const float* init_c_b;
  const float* f_beta_w; const float* f_beta_b;
  const float* lstm_w_ih; const float* lstm_w_hh; const float* lstm_b;
  const float* fc_w; const float* fc_b;
  float* out_preds; float* out_caps; float* out_declens; float* out_alphas; float* out_sortind;
  int* sort_ind; int* declen; int* caps_s;
  us* h_bf16; float* c; us* mean_bf16;
  us* waw_bf16; us* wihE_bf16; us* embs_bf16;
  us* att1; us* Wt; us* Wt2; us* Wt3; us* encT; us* awe_bf16;
  float* gpre; float* s1out; float* alpha_g;
  int* sync;
};

__device__ __forceinline__ us f2bf(float x){
  unsigned u = __float_as_uint(x);
  unsigned r = ((u >> 16) & 1u) + 0x7FFFu;
  return (us)((u + r) >> 16);
}
__device__ __forceinline__ unsigned pack2(float a, float b){
  return (unsigned)f2bf(a) | ((unsigned)f2bf(b) << 16);
}
__device__ __forceinline__ float bf2f(unsigned u16){ return __uint_as_float(u16 << 16); }
__device__ __forceinline__ float sigm(float x){ return 1.f/(1.f + __expf(-x)); }
__device__ __forceinline__ float tanh_f(float x){ return 1.f - 2.f/(__expf(2.f*x) + 1.f); }

// Coherent (cross-XCD) 32-bit ops: bypass L1/L2, land at the device coherent point.
__device__ __forceinline__ unsigned ald(const unsigned* p){
  return __hip_atomic_load(p, __ATOMIC_RELAXED, __HIP_MEMORY_SCOPE_AGENT);
}
__device__ __forceinline__ void ast(unsigned* p, unsigned v){
  __hip_atomic_store(p, v, __ATOMIC_RELAXED, __HIP_MEMORY_SCOPE_AGENT);
}
__device__ __forceinline__ float aldf(const float* p){
  return __uint_as_float(ald((const unsigned*)p));
}
__device__ __forceinline__ void astf(float* p, float v){
  ast((unsigned*)p, __float_as_uint(v));
}

using bf16x8 = __attribute__((ext_vector_type(8))) short;
using f32x4  = __attribute__((ext_vector_type(4))) float;
#define MFMA(a,b,c) __builtin_amdgcn_mfma_f32_16x16x32_bf16((a),(b),(c),0,0,0)

// padded LDS strides (us units): row stride % 64us == 16 -> dword-stride % 32 == 8
// -> fragment reads are at worst 2-way bank-aliased (free per G4 measurement).
#define HS 528     /* sm_h   row stride: 264 dw % 32 = 8 */
#define AS 2064    /* sm_awe row stride: 1032 dw % 32 = 8 */

// ---------------- prologue kernels ----------------

__global__ void k_meta(KParams p){
  __shared__ int len[32], sidx[32], sdecl[32];
  int tid = threadIdx.x;
  if (tid < 32) len[tid] = p.cap_lens[tid];
  __syncthreads();
  if (tid == 0){
    bool used[32];
    for (int i = 0; i < 32; i++) used[i] = false;
    for (int r = 0; r < 32; r++){
      int best = -1, bl = -2;
      for (int i = 0; i < 32; i++) if (!used[i] && len[i] > bl){ bl = len[i]; best = i; }
      used[best] = true; sidx[r] = best; sdecl[r] = bl - 1;
    }
  }
  __syncthreads();
  if (tid < 32){
    p.sort_ind[tid] = sidx[tid]; p.out_sortind[tid] = (float)sidx[tid];
    p.declen[tid]   = sdecl[tid]; p.out_declens[tid] = (float)sdecl[tid];
  }
  for (int idx = tid; idx < B_*L_; idx += 64){
    int b = idx / L_, l = idx - b*L_;
    int cv = p.captions[sidx[b]*L_ + l];
    p.caps_s[idx] = cv; p.out_caps[idx] = (float)cv;
  }
}

// 64x64 tile transpose: fp32 [R][C] -> bf16 [C][Rp], zero-pad rows >= R
__device__ void tp64(const float* src, us* dst, int R, int C, int Rp, int bi){
  __shared__ float tl[64][68];
  int tilesC = (C + 63) >> 6;
  int tr = bi / tilesC, tc = bi - tr*tilesC;
  int r0 = tr << 6, c0 = tc << 6;
  int tid = threadIdx.x;
  {
    int r = tid >> 2, cs = (tid & 3) << 4;
    bool rok = (r0 + r) < R;
    #pragma unroll
    for (int i = 0; i < 4; i++){
      int c = c0 + cs + i*4;
      float4 v = make_float4(0.f, 0.f, 0.f, 0.f);
      if (rok && c < C) v = *(const float4*)(src + (size_t)(r0 + r)*C + c);
      *(float4*)&tl[r][cs + i*4] = v;
    }
  }
  __syncthreads();
  {
    int c = tid >> 2, rs = (tid & 3) << 4;
    if (c0 + c < C && r0 + rs < Rp){
      us tmp[16];
      #pragma unroll
      for (int i = 0; i < 16; i++) tmp[i] = f2bf(tl[rs + i][c]);
      *(uint4*)(dst + (size_t)(c0 + c)*Rp + r0 + rs)     = *(uint4*)&tmp[0];
      *(uint4*)(dst + (size_t)(c0 + c)*Rp + r0 + rs + 8) = *(uint4*)&tmp[8];
    }
  }
}

__global__ void k_prep(KParams p){
  int bi = blockIdx.x, tid = threadIdx.x;
  if (bi < 512){                         // casts: enc_att_w, lstm_w_ih[:512]
    #pragma unroll
    for (int i = 0; i < 4; i++){
      int q = bi*1024 + i*256 + tid;
      const float4* src; uint2* dst; int qq;
      if (q < 262144){ src = (const float4*)p.enc_att_w; dst = (uint2*)p.waw_bf16;  qq = q; }
      else           { src = (const float4*)p.lstm_w_ih; dst = (uint2*)p.wihE_bf16; qq = q - 262144; }
      float4 v = src[qq];
      dst[qq] = make_uint2(pack2(v.x, v.y), pack2(v.z, v.w));
    }
  } else if (bi < 576){   tp64(p.dec_att_w, p.Wt,             512, 512,   512,  bi - 512);
  } else if (bi < 832){   tp64(p.f_beta_w,  p.Wt + 512*512,   512, 2048,  512,  bi - 576);
  } else if (bi < 1088){  tp64(p.lstm_w_hh, p.Wt + 2560*512,  512, 2048,  512,  bi - 832);
  } else if (bi < 2344){  tp64(p.fc_w,      p.Wt + 4608*512,  512, 10000, 512,  bi - 1088);
  } else if (bi < 3368){  tp64(p.lstm_w_ih + 512*2048, p.Wt2, 2048, 2048, 2048, bi - 2344);
  } else if (bi < 3624){  tp64(p.init_h_w,  p.Wt3,            2048, 512,  2048, bi - 3368);
  } else if (bi < 3880){  tp64(p.init_c_w,  p.Wt3 + 512*2048, 2048, 512,  2048, bi - 3624);
  } else if (bi < 4200){                 // embs gather -> bf16 [t][b][512]
    int q = (bi - 3880)*256 + tid;
    int row = q >> 7, qi = q & 127;
    int t = row >> 5, b = row & 31;
    int cap = p.caps_s[b*L_ + t];
    float4 v = ((const float4*)(p.emb + (size_t)cap*E_))[qi];
    ((uint2*)p.embs_bf16)[q] = make_uint2(pack2(v.x, v.y), pack2(v.z, v.w));
  } else {                               // encT: sorted enc [196][2048] -> [2048][208]
    int bl = bi - 4200;                  // 32*128
    int b = bl >> 7, ti = bl & 127;
    tp64(p.encoder_out + (size_t)p.sort_ind[b]*(P_*D_), p.encT + (size_t)b*D_*PP,
         196, 2048, PP, ti);
  }
}

// fused prologue GEMMs: bi<196 att1 (enc@enc_att_w, gathered fp32 A), else gpre (embs@wihE)
__global__ void __launch_bounds__(256) k_gemm2(KParams p){
  __shared__ us a_lds[128][40];
  __shared__ us b_lds[128][40];
  int bi = blockIdx.x;
  const us* Aq = nullptr; const float* Af = nullptr; const int* sidx = nullptr;
  const us* Bq; const float* bias; float* C; int N, K, obf, mode, ti;
  if (bi < 196){
    Af = p.encoder_out; sidx = p.sort_ind; Bq = p.waw_bf16; bias = p.enc_att_b;
    C = (float*)p.att1; N = 512; K = 2048; obf = 1; mode = 1; ti = bi;
  } else {
    Aq = p.embs_bf16; Bq = p.wihE_bf16; bias = p.lstm_b;
    C = p.gpre; N = 2048; K = 512; obf = 0; mode = 0; ti = bi - 196;
  }
  int ntiles = N >> 7;
  int bm = (ti / ntiles) << 7;
  int bn = (ti % ntiles) << 7;
  int tid = threadIdx.x;
  int wave = tid >> 6, lane = tid & 63;
  int wr = (wave >> 1) << 6, wc = (wave & 1) << 6;
  int la = lane & 15, lq = lane >> 4;
  f32x4 acc[4][4] = {};
  for (int k0 = 0; k0 < K; k0 += 32){
    {
      int r = tid >> 1, ch = (tid & 1) << 4;
      if (mode == 0){
        const uint4* asrc = (const uint4*)(Aq + (size_t)(bm + r)*K + k0 + ch);
        uint4 v0 = asrc[0], v1 = asrc[1];
        *(uint4*)&a_lds[r][ch]     = v0;
        *(uint4*)&a_lds[r][ch + 8] = v1;
      } else {
        int g = bm + r; int b = g / 196; int pp = g - b*196;
        const float4* as = (const float4*)(Af + ((size_t)sidx[b]*196 + pp)*2048 + k0 + ch);
        float4 f0 = as[0], f1 = as[1], f2 = as[2], f3 = as[3];
        *(uint4*)&a_lds[r][ch]     = make_uint4(pack2(f0.x,f0.y), pack2(f0.z,f0.w), pack2(f1.x,f1.y), pack2(f1.z,f1.w));
        *(uint4*)&a_lds[r][ch + 8] = make_uint4(pack2(f2.x,f2.y), pack2(f2.z,f2.w), pack2(f3.x,f3.y), pack2(f3.z,f3.w));
      }
      int kk = tid >> 3, n0 = (tid & 7) << 4;
      const us* bs = Bq + (size_t)(k0 + kk)*N + bn + n0;
      uint4 bv0 = *(const uint4*)bs, bv1 = *(const uint4*)(bs + 8);
      unsigned vals[8] = {bv0.x, bv0.y, bv0.z, bv0.w, bv1.x, bv1.y, bv1.z, bv1.w};
      #pragma unroll
      for (int i = 0; i < 8; i++){
        b_lds[n0 + 2*i][kk]     = (us)(vals[i] & 0xffffu);
        b_lds[n0 + 2*i + 1][kk] = (us)(vals[i] >> 16);
      }
    }
    __syncthreads();
    bf16x8 af[4], bfr[4];
    #pragma unroll
    for (int mt = 0; mt < 4; mt++) af[mt]  = *(const bf16x8*)&a_lds[wr + mt*16 + la][lq*8];
    #pragma unroll
    for (int nt = 0; nt < 4; nt++) bfr[nt] = *(const bf16x8*)&b_lds[wc + nt*16 + la][lq*8];
    #pragma unroll
    for (int mt = 0; mt < 4; mt++)
      #pragma unroll
      for (int nt = 0; nt < 4; nt++)
        acc[mt][nt] = MFMA(af[mt], bfr[nt], acc[mt][nt]);
    __syncthreads();
  }
  #pragma unroll
  for (int mt = 0; mt < 4; mt++){
    int row0 = bm + wr + mt*16 + lq*4;
    #pragma unroll
    for (int nt = 0; nt < 4; nt++){
      int coln = bn + wc + nt*16 + la;
      float bb = bias ? bias[coln] : 0.f;
      #pragma unroll
      for (int r = 0; r < 4; r++){
        float v = acc[mt][nt][r] + bb;
        if (obf) ((us*)C)[(size_t)(row0 + r)*N + coln] = f2bf(v);
        else     C[(size_t)(row0 + r)*N + coln] = v;
      }
    }
  }
}

// ---------------- cooperative scan kernel (4 groups x 64 blocks x 512 threads) ----
// Round-10: 8 batches per group -> every M=16 MFMA carries 8 valid rows (was 4).
// Same tile count serves 2x batches: device-wide tile-jobs halve, fc chains drop
// 3->2, G1 is <=1 job/wave, weight tiles are fetched by 4 groups instead of 8
// (halved per-XCD L2-fill). Attention = jb<8 -> one straggler block per XCD
// (r7 piled all on XCDs 0-3). Everything else is the proven r7 config: fence-free
// coherence, 512-thread blocks (2 waves/SIMD), 4 barriers/step (r9 fusion
// reverted), r7 tree barrier verbatim, padded LDS.
// Topology: gb=blk>>6, jb=blk&63 -> XCD = jb%8; tile = f(jb,wv) -> same-tile
// blocks of all 4 groups co-locate on one XCD L2.

__device__ __forceinline__ void gsync_g(int* sc, int gen, int jb){
  __syncthreads();
  if (threadIdx.x == 0){
    int old = __hip_atomic_fetch_add(&sc[(jb & 7)*32], 1, __ATOMIC_RELEASE, __HIP_MEMORY_SCOPE_AGENT);
    bool last = false;
    if (old == gen*8 - 1){
      int old2 = __hip_atomic_fetch_add(&sc[512], 1, __ATOMIC_RELAXED, __HIP_MEMORY_SCOPE_AGENT);
      if (old2 == gen*8 - 1){
        __hip_atomic_store(&sc[544], gen, __ATOMIC_RELEASE, __HIP_MEMORY_SCOPE_AGENT);
        last = true;
      }
    }
    if (!last){
      while (__hip_atomic_load(&sc[544], __ATOMIC_RELAXED, __HIP_MEMORY_SCOPE_AGENT) < gen)
        __builtin_amdgcn_s_sleep(2);
    }
  }
  __syncthreads();
}

// fc over slots: M=16 tile with 8 valid rows (group batches), h from padded LDS stage
__device__ __forceinline__ void fc_run(const KParams& p, const int* sm_dl, const us* hlds,
                                       int b0, int slot, int nslots, int niter,
                                       int la, int lq, int tpred){
  bf16x8 afr[16];
  #pragma unroll
  for (int ks = 0; ks < 16; ks++) afr[ks] = *(const bf16x8*)&hlds[(la & 7)*HS + lq*8 + ks*32];
  for (int it = 0; it < niter; it++){
    int tile = slot + it*nslots;
    if (tile < 625){
      int n0 = tile*16;
      const us* wp = p.Wt + ((size_t)(4608 + n0 + la))*512 + lq*8;
      f32x4 ac = {};
      #pragma unroll
      for (int ks = 0; ks < 16; ks++){
        bf16x8 bB = *(const bf16x8*)(wp + ks*32);
        ac = MFMA(afr[ks], bB, ac);
      }
      if (lq < 2){
        int v = n0 + la;
        float bb = p.fc_b[v];
        #pragma unroll
        for (int r = 0; r < 4; r++){
          int b = b0 + lq*4 + r;
          bool act = tpred < sm_dl[b];
          p.out_preds[((size_t)b*T_ + tpred)*V_ + v] = act ? (ac[r] + bb) : 0.f;
        }
      }
    }
  }
}

__global__ void __launch_bounds__(512, 2) k_loop(KParams p){
  const int tid = threadIdx.x, blk = blockIdx.x;
  const int gb = blk >> 6, jb = blk & 63, b0 = gb*8;  // 4 groups x 64 blocks; XCD = jb%8
  const int wv = tid >> 6, lane = tid & 63, la = lane & 15, lq = lane >> 4;
  int* sc = p.sync + gb*1024;
  __shared__ float sm_att2[512], sm_fw[512], sm_red[16];
  __shared__ float sm_a4f[8*PP];
  __shared__ float gq2[4][2][16][8];
  __shared__ int sm_dl[32];
  __shared__ us sm_h[8*HS];      // coherent-staged h rows (padded)
  __shared__ us sm_awe[8*AS];    // coherent-staged awe / mean (padded)
  int gen = 0;

  if (tid < 32) sm_dl[tid] = p.declen[tid];
  __syncthreads();

  // ===== GP1: mean over p — 32 d/block x 8 b, 2 threads per (d,b) =====
  {
    int part = tid & 1, pair = tid >> 1;
    int d = jb*32 + (pair >> 3), b = b0 + (pair & 7);
    const uint4* rp = (const uint4*)(p.encT + ((size_t)b*D_ + d)*PP);
    int cs = part*13;
    float s = 0.f;
    for (int i = cs; i < cs + 13; i++){
      uint4 u = rp[i];
      s += bf2f(u.x&0xffffu)+bf2f(u.x>>16)+bf2f(u.y&0xffffu)+bf2f(u.y>>16)
         + bf2f(u.z&0xffffu)+bf2f(u.z>>16)+bf2f(u.w&0xffffu)+bf2f(u.w>>16);
    }
    s += __shfl_xor(s, 1);
    float mv = s*(1.f/196.f);
    float ov = __shfl_xor(mv, 16);          // partner: d^1 (tid bit4), same b
    if (part == 0 && !(tid & 16))
      ast((unsigned*)p.mean_bf16 + ((size_t)b*1024 + (d >> 1)), pack2(mv, ov));
  }
  gsync_g(sc, ++gen, jb);
  // ===== GP2: h0/c0 = mean @ Wt3 — 64 tiles over blocks 0..7 x 8 waves =====
  if (jb < 8){
    {
      unsigned* dst = (unsigned*)sm_awe;
      const unsigned* src = (const unsigned*)p.mean_bf16 + (size_t)b0*1024;
      for (int i = tid; i < 8192; i += 512) dst[(i >> 10)*(AS >> 1) + (i & 1023)] = ald(src + i);
    }
    __syncthreads();
    int slot = jb*8 + wv;
    const us* wp = p.Wt3 + ((size_t)(slot*16 + la))*2048 + lq*8;
    const us* ap = sm_awe + (la & 7)*AS + lq*8;
    f32x4 ac0 = {}, ac1 = {};
    for (int ki = 0; ki < 64; ki += 2){
      bf16x8 aA = *(const bf16x8*)(ap + ki*32);
      bf16x8 bB = *(const bf16x8*)(wp + ki*32);
      ac0 = MFMA(aA, bB, ac0);
      bf16x8 aA2 = *(const bf16x8*)(ap + ki*32 + 32);
      bf16x8 bB2 = *(const bf16x8*)(wp + ki*32 + 32);
      ac1 = MFMA(aA2, bB2, ac1);
    }
    f32x4 ac = ac0 + ac1;
    int col = slot*16 + la;
    if (col < 512){
      #pragma unroll
      for (int r = 0; r < 4; r++){
        float v0 = ac[r] + p.init_h_b[col];
        float v1 = __shfl_xor(v0, 1);       // partner col^1, same row
        if (lq < 2 && !(la & 1))
          ast((unsigned*)p.h_bf16 + (((size_t)(b0 + lq*4 + r)*512 + col) >> 1), pack2(v0, v1));
      }
    } else {
      #pragma unroll
      for (int r = 0; r < 4; r++)
        if (lq < 2) astf(&p.c[(size_t)(b0 + lq*4 + r)*512 + col - 512], ac[r] + p.init_c_b[col - 512]);
    }
  }
  gsync_g(sc, ++gen, jb);

  for (int t = 0; t < T_; ++t){
    // ===== stage h (coherent) -> padded LDS (8 rows) =====
    {
      unsigned* dst = (unsigned*)sm_h;
      const unsigned* src = (const unsigned*)p.h_bf16 + (size_t)b0*256;
      for (int i = tid; i < 2048; i += 512) dst[(i >> 8)*(HS >> 1) + (i & 255)] = ald(src + i);
    }
    __syncthreads();
    // ===== G1: s1out = h @ Wt — 288 tiles over 512 wave-slots, <=1 each =====
    {
      int slot = jb*8 + wv;
      if (slot < 288){
        bf16x8 afr[16];
        #pragma unroll
        for (int ks = 0; ks < 16; ks++) afr[ks] = *(const bf16x8*)&sm_h[(la & 7)*HS + lq*8 + ks*32];
        int n0 = slot*16;
        const us* wp = p.Wt + ((size_t)(n0 + la))*512 + lq*8;
        f32x4 ac = {};
        #pragma unroll
        for (int ks = 0; ks < 16; ks++){
          bf16x8 bB = *(const bf16x8*)(wp + ks*32);
          ac = MFMA(afr[ks], bB, ac);
        }
        if (lq < 2){
          #pragma unroll
          for (int r = 0; r < 4; r++) astf(&p.s1out[(size_t)(b0 + lq*4 + r)*4608 + n0 + la], ac[r]);
        }
      }
    }
    gsync_g(sc, ++gen, jb);
    // ===== G2: blocks 0..7 attention softmax (1/XCD) | blocks 8..63 fc preds[t-1] =====
    if (jb < 8){
      int b = b0 + jb;
      for (int cc = tid; cc < 512; cc += 512){
        sm_att2[cc] = aldf(&p.s1out[(size_t)b*4608 + cc]) + p.dec_att_b[cc];
        sm_fw[cc]   = p.full_att_w[cc];
      }
      __syncthreads();
      float ee = -1e30f;
      if (tid < 196){
        const uint4* row = (const uint4*)(p.att1 + ((size_t)(b*196 + tid))*512);
        float s = 0.f;
        #pragma unroll 8
        for (int i = 0; i < 64; i++){
          uint4 u = row[i];
          float4 a0 = *(const float4*)&sm_att2[i*8], a1 = *(const float4*)&sm_att2[i*8+4];
          float4 f0 = *(const float4*)&sm_fw[i*8],   f1 = *(const float4*)&sm_fw[i*8+4];
          s += fmaxf(bf2f(u.x&0xffffu)+a0.x,0.f)*f0.x + fmaxf(bf2f(u.x>>16)+a0.y,0.f)*f0.y
             + fmaxf(bf2f(u.y&0xffffu)+a0.z,0.f)*f0.z + fmaxf(bf2f(u.y>>16)+a0.w,0.f)*f0.w
             + fmaxf(bf2f(u.z&0xffffu)+a1.x,0.f)*f1.x + fmaxf(bf2f(u.z>>16)+a1.y,0.f)*f1.y
             + fmaxf(bf2f(u.w&0xffffu)+a1.z,0.f)*f1.z + fmaxf(bf2f(u.w>>16)+a1.w,0.f)*f1.w;
        }
        ee = s;
      }
      float v = ee;
      #pragma unroll
      for (int off = 32; off; off >>= 1) v = fmaxf(v, __shfl_xor(v, off));
      if (lane == 0) sm_red[wv] = v;
      __syncthreads();
      float m = sm_red[0];
      #pragma unroll
      for (int i = 1; i < 8; i++) m = fmaxf(m, sm_red[i]);
      float ex = (tid < 196) ? __expf(ee - m) : 0.f;
      float sv = ex;
      #pragma unroll
      for (int off = 32; off; off >>= 1) sv += __shfl_xor(sv, off);
      if (lane == 0) sm_red[8 + wv] = sv;
      __syncthreads();
      float ssum = sm_red[8];
      #pragma unroll
      for (int i = 1; i < 8; i++) ssum += sm_red[8 + i];
      if (tid < 196){
        float a = ex/ssum;
        astf(&p.alpha_g[b*PP + tid], a);
        bool act = t < sm_dl[b];
        p.out_alphas[((size_t)b*T_ + t)*P_ + tid] = act ? a : 0.f;
      } else if (tid < PP) astf(&p.alpha_g[b*PP + tid], 0.f);
    } else if (t > 0){
      fc_run(p, sm_dl, sm_h, b0, (jb - 8)*8 + wv, 448, 2, la, lq, t - 1);
    }
    gsync_g(sc, ++gen, jb);
    // ===== G3: awe = gate * (alpha @ enc) — 32 d/block x 8 b, 2 thr/(d,b) =====
    {
      for (int i = tid; i < 8*PP; i += 512) sm_a4f[i] = aldf(&p.alpha_g[b0*PP + i]);
      __syncthreads();
      int part = tid & 1, pair = tid >> 1;
      int d = jb*32 + (pair >> 3), b = b0 + (pair & 7);
      const float* al = sm_a4f + (pair & 7)*PP;
      const uint4* rp = (const uint4*)(p.encT + ((size_t)b*D_ + d)*PP);
      int cs = part*13;
      float acc = 0.f;
      for (int i = cs; i < cs + 13; i++){
        uint4 u = rp[i];
        float4 a0 = *(const float4*)(al + i*8), a1 = *(const float4*)(al + i*8 + 4);
        acc += a0.x*bf2f(u.x&0xffffu) + a0.y*bf2f(u.x>>16)
             + a0.z*bf2f(u.y&0xffffu) + a0.w*bf2f(u.y>>16)
             + a1.x*bf2f(u.z&0xffffu) + a1.y*bf2f(u.z>>16)
             + a1.z*bf2f(u.w&0xffffu) + a1.w*bf2f(u.w>>16);
      }
      acc += __shfl_xor(acc, 1);
      float gate = sigm(aldf(&p.s1out[(size_t)b*4608 + 512 + d]) + p.f_beta_b[d]);
      float wv_ = acc*gate;
      float ov = __shfl_xor(wv_, 16);       // partner: d^1 (tid bit4), same b
      if (part == 0 && !(tid & 16))
        ast((unsigned*)p.awe_bf16 + ((size_t)b*1024 + (d >> 1)), pack2(wv_, ov));
    }
    gsync_g(sc, ++gen, jb);
    // ===== G4: g = gpre + ghh + awe@Wt2 (blocks 0..31: gate x K-half/wave) + LSTM =====
    if (jb < 32){
      {
        unsigned* dst = (unsigned*)sm_awe;
        const unsigned* src = (const unsigned*)p.awe_bf16 + (size_t)b0*1024;
        for (int i = tid; i < 8192; i += 512) dst[(i >> 10)*(AS >> 1) + (i & 1023)] = ald(src + i);
      }
      __syncthreads();
      int q = wv >> 1, kh = wv & 1, hc0 = jb*16;
      const us* wp = p.Wt2 + ((size_t)(q*512 + hc0 + la))*2048 + kh*1024 + lq*8;
      const us* ap = sm_awe + (la & 7)*AS + kh*1024 + lq*8;
      f32x4 ac0 = {}, ac1 = {};
      for (int ki = 0; ki < 32; ki += 2){
        bf16x8 aA = *(const bf16x8*)(ap + ki*32);
        bf16x8 bB = *(const bf16x8*)(wp + ki*32);
        ac0 = MFMA(aA, bB, ac0);
        bf16x8 aA2 = *(const bf16x8*)(ap + ki*32 + 32);
        bf16x8 bB2 = *(const bf16x8*)(wp + ki*32 + 32);
        ac1 = MFMA(aA2, bB2, ac1);
      }
      f32x4 ac = ac0 + ac1;
      if (lq < 2){
        #pragma unroll
        for (int r = 0; r < 4; r++) gq2[q][kh][la][lq*4 + r] = ac[r];
      }
      __syncthreads();
      if (tid < 128){
        int hc = hc0 + (tid & 15), r = tid >> 4;   // r = 0..7
        int b = b0 + r;
        float gv[4];
        #pragma unroll
        for (int qq = 0; qq < 4; qq++)
          gv[qq] = gq2[qq][0][tid & 15][r] + gq2[qq][1][tid & 15][r]
                 + aldf(&p.s1out[(size_t)b*4608 + 2560 + qq*512 + hc])
                 + p.gpre[((size_t)t*32 + b)*2048 + qq*512 + hc];
        float cold = aldf(&p.c[(size_t)b*512 + hc]);
        float cn = sigm(gv[1])*cold + sigm(gv[0])*tanh_f(gv[2]);
        float hn = sigm(gv[3])*tanh_f(cn);
        float hv1 = __shfl_xor(hn, 1);      // partner hc^1, same b
        if (t < sm_dl[b]){
          astf(&p.c[(size_t)b*512 + hc], cn);
          if (!(tid & 1))
            ast((unsigned*)p.h_bf16 + (((size_t)b*512 + hc) >> 1), pack2(hn, hv1));
        }
      }
    }
    gsync_g(sc, ++gen, jb);
  }
  // ===== epilogue: preds[T-1] (all 64 blocks x 8 waves per group) =====
  {
    unsigned* dst = (unsigned*)sm_h;
    const unsigned* src = (const unsigned*)p.h_bf16 + (size_t)b0*256;
    for (int i = tid; i < 2048; i += 512) dst[(i >> 8)*(HS >> 1) + (i & 255)] = ald(src + i);
  }
  __syncthreads();
  fc_run(p, sm_dl, sm_h, b0, jb*8 + wv, 512, 2, la, lq, T_ - 1);
}

// ---------------- host launcher ----------------

extern "C" void kernel_launch(void* const* d_in, const int* in_sizes, int n_in,
                              void* d_out, int out_size, void* d_ws, size_t ws_size,
                              hipStream_t stream){
  (void)in_sizes; (void)n_in; (void)out_size; (void)ws_size;
  KParams p;
  p.encoder_out = (const float*)d_in[0];
  p.captions    = (const int*)d_in[1];
  p.cap_lens    = (const int*)d_in[2];
  p.enc_att_w   = (const float*)d_in[3];  p.enc_att_b = (const float*)d_in[4];
  p.dec_att_w   = (const float*)d_in[5];  p.dec_att_b = (const float*)d_in[6];
  p.full_att_w  = (const float*)d_in[7];  p.full_att_b = (const float*)d_in[8];
  p.emb         = (const float*)d_in[9];
  p.init_h_w    = (const float*)d_in[10]; p.init_h_b = (const float*)d_in[11];
  p.init_c_w    = (const float*)d_in[12]; p.init_c_b = (const float*)d_in[13];
  p.f_beta_w    = (const float*)d_in[14]; p.f_beta_b = (const float*)d_in[15];
  p.lstm_w_ih   = (const float*)d_in[16]; p.lstm_w_hh = (const float*)d_in[17]; p.lstm_b = (const float*)d_in[18];
  p.fc_w        = (const float*)d_in[19]; p.fc_b = (const float*)d_in[20];

  float* out = (float*)d_out;
  p.out_preds   = out;
  p.out_caps    = out + 6400000;
  p.out_declens = out + 6400672;
  p.out_alphas  = out + 6400704;
  p.out_sortind = out + 6526144;

  char* w = (char*)d_ws; size_t off = 0;
  auto alloc = [&](size_t bytes)->char*{ char* r = w + off; off = (off + bytes + 255) & ~(size_t)255; return r; };
  p.sort_ind  = (int*)alloc(128);
  p.declen    = (int*)alloc(128);
  p.caps_s    = (int*)alloc(2688);
  p.h_bf16    = (us*)alloc(32768);
  p.c         = (float*)alloc(65536);
  p.mean_bf16 = (us*)alloc(131072);
  p.waw_bf16  = (us*)alloc(2097152);
  p.wihE_bf16 = (us*)alloc(2097152);
  p.embs_bf16 = (us*)alloc(655360);
  p.att1      = (us*)alloc(6422528);     // [6272][512] bf16
  p.Wt        = (us*)alloc(14958592);    // [14608][512] bf16
  p.Wt2       = (us*)alloc(8388608);     // [2048][2048] bf16
  p.Wt3       = (us*)alloc(4194304);     // [1024][2048] bf16
  p.encT      = (us*)alloc(27262976);    // [32][2048][208] bf16
  p.gpre      = (float*)alloc(5242880);  // [20][32][2048]
  p.s1out     = (float*)alloc(589824);   // [32][4608]
  p.alpha_g   = (float*)alloc(26624);    // [32][208]
  p.awe_bf16  = (us*)alloc(131072);      // [32][2048]
  p.sync      = (int*)alloc(32768);      // 4 groups x 1024 ints

  hipMemsetAsync(p.sync, 0, 32768, stream);
  hipLaunchKernelGGL(k_meta,  dim3(1),    dim3(64),  0, stream, p);
  hipLaunchKernelGGL(k_prep,  dim3(8296), dim3(256), 0, stream, p);
  hipLaunchKernelGGL(k_gemm2, dim3(276),  dim3(256), 0, stream, p);
  void* args[] = { (void*)&p };
  hipLaunchCooperativeKernel((void*)k_loop, dim3(256), dim3(512), args, 0, stream);
}

// Round 11
// 1523.025 us; speedup vs baseline: 1.0988x; 1.0238x over previous
//
#include <hip/hip_runtime.h>

#define B_ 32
#define P_ 196
#define D_ 2048
#define A_ 512
#define E_ 512
#define H_ 512
#define V_ 10000
#define L_ 21
#define T_ 20
#define PP 208              /* padded P for encT rows (mult of 16) */

typedef unsigned short us;

struct KParams {
  const float* encoder_out; const int* captions; const int* cap_lens;
  const float* enc_att_w; const float* enc_att_b;
  const float* dec_att_w; const float* dec_att_b;
  const float* full_att_w; const float* full_att_b;
  const float* emb;
  const float* init_h_w; const float* init_h_b;
  const float* init_c_w; const float* init_c_b;
  const float* f_beta_w; const float* f_beta_b;
  const float* lstm_w_ih; const float* lstm_w_hh; const float* lstm_b;
  const float* fc_w; const float* fc_b;
  float* out_preds; float* out_caps; float* out_declens; float* out_alphas; float* out_sortind;
  int* sort_ind; int* declen; int* caps_s;
  us* h_bf16; float* c; us* mean_bf16;
  us* waw_bf16; us* wihE_bf16; us* embs_bf16;
  us* att1; us* Wt; us* Wt2; us* Wt3; us* encT; us* awe_bf16;
  float* gpre; float* s1out; float* alpha_g;
  int* sync;
};

__device__ __forceinline__ us f2bf(float x){
  unsigned u = __float_as_uint(x);
  unsigned r = ((u >> 16) & 1u) + 0x7FFFu;
  return (us)((u + r) >> 16);
}
__device__ __forceinline__ unsigned pack2(float a, float b){
  return (unsigned)f2bf(a) | ((unsigned)f2bf(b) << 16);
}
__device__ __forceinline__ float bf2f(unsigned u16){ return __uint_as_float(u16 << 16); }
__device__ __forceinline__ float sigm(float x){ return 1.f/(1.f + __expf(-x)); }
__device__ __forceinline__ float tanh_f(float x){ return 1.f - 2.f/(__expf(2.f*x) + 1.f); }

// Coherent (cross-XCD) 32-bit ops: bypass L1/L2, land at the device coherent point.
__device__ __forceinline__ unsigned ald(const unsigned* p){
  return __hip_atomic_load(p, __ATOMIC_RELAXED, __HIP_MEMORY_SCOPE_AGENT);
}
__device__ __forceinline__ void ast(unsigned* p, unsigned v){
  __hip_atomic_store(p, v, __ATOMIC_RELAXED, __HIP_MEMORY_SCOPE_AGENT);
}
__device__ __forceinline__ float aldf(const float* p){
  return __uint_as_float(ald((const unsigned*)p));
}
__device__ __forceinline__ void astf(float* p, float v){
  ast((unsigned*)p, __float_as_uint(v));
}

using bf16x8 = __attribute__((ext_vector_type(8))) short;
using f32x4  = __attribute__((ext_vector_type(4))) float;
#define MFMA(a,b,c) __builtin_amdgcn_mfma_f32_16x16x32_bf16((a),(b),(c),0,0,0)

// padded LDS strides (us units): row stride dw % 32 == 4 -> 8 consecutive rows map
// to 8 DISTINCT banks (r*4 mod 32); the la / la+8 lane pair reads the same address
// (free broadcast). r10's 528/2064 (dw%32==8) aliased rows 4-way -> 4.6e6 conflicts.
#define HS 520     /* sm_h   row stride: 260 dw % 32 = 4 */
#define AS 2056    /* sm_awe row stride: 1028 dw % 32 = 4 */

// ---------------- prologue kernels ----------------

__global__ void k_meta(KParams p){
  __shared__ int len[32], sidx[32], sdecl[32];
  int tid = threadIdx.x;
  if (tid < 32) len[tid] = p.cap_lens[tid];
  __syncthreads();
  if (tid == 0){
    bool used[32];
    for (int i = 0; i < 32; i++) used[i] = false;
    for (int r = 0; r < 32; r++){
      int best = -1, bl = -2;
      for (int i = 0; i < 32; i++) if (!used[i] && len[i] > bl){ bl = len[i]; best = i; }
      used[best] = true; sidx[r] = best; sdecl[r] = bl - 1;
    }
  }
  __syncthreads();
  if (tid < 32){
    p.sort_ind[tid] = sidx[tid]; p.out_sortind[tid] = (float)sidx[tid];
    p.declen[tid]   = sdecl[tid]; p.out_declens[tid] = (float)sdecl[tid];
  }
  for (int idx = tid; idx < B_*L_; idx += 64){
    int b = idx / L_, l = idx - b*L_;
    int cv = p.captions[sidx[b]*L_ + l];
    p.caps_s[idx] = cv; p.out_caps[idx] = (float)cv;
  }
}

// 64x64 tile transpose: fp32 [R][C] -> bf16 [C][Rp], zero-pad rows >= R
__device__ void tp64(const float* src, us* dst, int R, int C, int Rp, int bi){
  __shared__ float tl[64][68];
  int tilesC = (C + 63) >> 6;
  int tr = bi / tilesC, tc = bi - tr*tilesC;
  int r0 = tr << 6, c0 = tc << 6;
  int tid = threadIdx.x;
  {
    int r = tid >> 2, cs = (tid & 3) << 4;
    bool rok = (r0 + r) < R;
    #pragma unroll
    for (int i = 0; i < 4; i++){
      int c = c0 + cs + i*4;
      float4 v = make_float4(0.f, 0.f, 0.f, 0.f);
      if (rok && c < C) v = *(const float4*)(src + (size_t)(r0 + r)*C + c);
      *(float4*)&tl[r][cs + i*4] = v;
    }
  }
  __syncthreads();
  {
    int c = tid >> 2, rs = (tid & 3) << 4;
    if (c0 + c < C && r0 + rs < Rp){
      us tmp[16];
      #pragma unroll
      for (int i = 0; i < 16; i++) tmp[i] = f2bf(tl[rs + i][c]);
      *(uint4*)(dst + (size_t)(c0 + c)*Rp + r0 + rs)     = *(uint4*)&tmp[0];
      *(uint4*)(dst + (size_t)(c0 + c)*Rp + r0 + rs + 8) = *(uint4*)&tmp[8];
    }
  }
}

// prep1: only what k_big's GEMMs depend on — casts (enc_att_w, lstm_w_ih[:512]) + embs
__global__ void k_prep1(KParams p){
  int bi = blockIdx.x, tid = threadIdx.x;
  if (bi < 512){
    #pragma unroll
    for (int i = 0; i < 4; i++){
      int q = bi*1024 + i*256 + tid;
      const float4* src; uint2* dst; int qq;
      if (q < 262144){ src = (const float4*)p.enc_att_w; dst = (uint2*)p.waw_bf16;  qq = q; }
      else           { src = (const float4*)p.lstm_w_ih; dst = (uint2*)p.wihE_bf16; qq = q - 262144; }
      float4 v = src[qq];
      dst[qq] = make_uint2(pack2(v.x, v.y), pack2(v.z, v.w));
    }
  } else {                               // embs gather -> bf16 [t][b][512]
    int q = (bi - 512)*256 + tid;
    int row = q >> 7, qi = q & 127;
    int t = row >> 5, b = row & 31;
    int cap = p.caps_s[b*L_ + t];
    float4 v = ((const float4*)(p.emb + (size_t)cap*E_))[qi];
    ((uint2*)p.embs_bf16)[q] = make_uint2(pack2(v.x, v.y), pack2(v.z, v.w));
  }
}

// k_big: GEMMs (blocks 0..275, scheduled first) + all big transposes (independent
// of the GEMMs — both depend only on prep1/meta) in ONE launch so they overlap.
__global__ void __launch_bounds__(256) k_big(KParams p){
  int bi = blockIdx.x, tid = threadIdx.x;
  if (bi >= 276){
    int bj = bi - 276;
    if      (bj < 64)   tp64(p.dec_att_w, p.Wt,             512, 512,   512,  bj);
    else if (bj < 320)  tp64(p.f_beta_w,  p.Wt + 512*512,   512, 2048,  512,  bj - 64);
    else if (bj < 576)  tp64(p.lstm_w_hh, p.Wt + 2560*512,  512, 2048,  512,  bj - 320);
    else if (bj < 1832) tp64(p.fc_w,      p.Wt + 4608*512,  512, 10000, 512,  bj - 576);
    else if (bj < 2856) tp64(p.lstm_w_ih + 512*2048, p.Wt2, 2048, 2048, 2048, bj - 1832);
    else if (bj < 3112) tp64(p.init_h_w,  p.Wt3,            2048, 512,  2048, bj - 2856);
    else if (bj < 3368) tp64(p.init_c_w,  p.Wt3 + 512*2048, 2048, 512,  2048, bj - 3112);
    else {                               // encT: sorted enc [196][2048] -> [2048][208]
      int bl = bj - 3368;                // 32*128
      int b = bl >> 7, ti = bl & 127;
      tp64(p.encoder_out + (size_t)p.sort_ind[b]*(P_*D_), p.encT + (size_t)b*D_*PP,
           196, 2048, PP, ti);
    }
    return;
  }
  // fused GEMMs: bi<196 att1 (enc@enc_att_w, gathered fp32 A), else gpre (embs@wihE)
  __shared__ us a_lds[128][40];
  __shared__ us b_lds[128][40];
  const us* Aq = nullptr; const float* Af = nullptr; const int* sidx = nullptr;
  const us* Bq; const float* bias; float* C; int N, K, obf, mode, ti;
  if (bi < 196){
    Af = p.encoder_out; sidx = p.sort_ind; Bq = p.waw_bf16; bias = p.enc_att_b;
    C = (float*)p.att1; N = 512; K = 2048; obf = 1; mode = 1; ti = bi;
  } else {
    Aq = p.embs_bf16; Bq = p.wihE_bf16; bias = p.lstm_b;
    C = p.gpre; N = 2048; K = 512; obf = 0; mode = 0; ti = bi - 196;
  }
  int ntiles = N >> 7;
  int bm = (ti / ntiles) << 7;
  int bn = (ti % ntiles) << 7;
  int wave = tid >> 6, lane = tid & 63;
  int wr = (wave >> 1) << 6, wc = (wave & 1) << 6;
  int la = lane & 15, lq = lane >> 4;
  f32x4 acc[4][4] = {};
  for (int k0 = 0; k0 < K; k0 += 32){
    {
      int r = tid >> 1, ch = (tid & 1) << 4;
      if (mode == 0){
        const uint4* asrc = (const uint4*)(Aq + (size_t)(bm + r)*K + k0 + ch);
        uint4 v0 = asrc[0], v1 = asrc[1];
        *(uint4*)&a_lds[r][ch]     = v0;
        *(uint4*)&a_lds[r][ch + 8] = v1;
      } else {
        int g = bm + r; int b = g / 196; int pp = g - b*196;
        const float4* as = (const float4*)(Af + ((size_t)sidx[b]*196 + pp)*2048 + k0 + ch);
        float4 f0 = as[0], f1 = as[1], f2 = as[2], f3 = as[3];
        *(uint4*)&a_lds[r][ch]     = make_uint4(pack2(f0.x,f0.y), pack2(f0.z,f0.w), pack2(f1.x,f1.y), pack2(f1.z,f1.w));
        *(uint4*)&a_lds[r][ch + 8] = make_uint4(pack2(f2.x,f2.y), pack2(f2.z,f2.w), pack2(f3.x,f3.y), pack2(f3.z,f3.w));
      }
      int kk = tid >> 3, n0 = (tid & 7) << 4;
      const us* bs = Bq + (size_t)(k0 + kk)*N + bn + n0;
      uint4 bv0 = *(const uint4*)bs, bv1 = *(const uint4*)(bs + 8);
      unsigned vals[8] = {bv0.x, bv0.y, bv0.z, bv0.w, bv1.x, bv1.y, bv1.z, bv1.w};
      #pragma unroll
      for (int i = 0; i < 8; i++){
        b_lds[n0 + 2*i][kk]     = (us)(vals[i] & 0xffffu);
        b_lds[n0 + 2*i + 1][kk] = (us)(vals[i] >> 16);
      }
    }
    __syncthreads();
    bf16x8 af[4], bfr[4];
    #pragma unroll
    for (int mt = 0; mt < 4; mt++) af[mt]  = *(const bf16x8*)&a_lds[wr + mt*16 + la][lq*8];
    #pragma unroll
    for (int nt = 0; nt < 4; nt++) bfr[nt] = *(const bf16x8*)&b_lds[wc + nt*16 + la][lq*8];
    #pragma unroll
    for (int mt = 0; mt < 4; mt++)
      #pragma unroll
      for (int nt = 0; nt < 4; nt++)
        acc[mt][nt] = MFMA(af[mt], bfr[nt], acc[mt][nt]);
    __syncthreads();
  }
  #pragma unroll
  for (int mt = 0; mt < 4; mt++){
    int row0 = bm + wr + mt*16 + lq*4;
    #pragma unroll
    for (int nt = 0; nt < 4; nt++){
      int coln = bn + wc + nt*16 + la;
      float bb = bias ? bias[coln] : 0.f;
      #pragma unroll
      for (int r = 0; r < 4; r++){
        float v = acc[mt][nt][r] + bb;
        if (obf) ((us*)C)[(size_t)(row0 + r)*N + coln] = f2bf(v);
        else     C[(size_t)(row0 + r)*N + coln] = v;
      }
    }
  }
}

// ---------------- cooperative scan kernel (4 groups x 64 blocks x 512 threads) ----
// r10 structure (best measured): 8 batches/group (M=16 MFMA carries 8 valid rows),
// fence-free coherence, 512-thread blocks (2 waves/SIMD), 4 barriers/step, r7 tree
// barrier. r11: conflict-free padded strides (HS/AS: row dw%32==4).
// Topology: gb=blk>>6, jb=blk&63 -> XCD = jb%8; tile = f(jb,wv) -> same-tile
// blocks of all 4 groups co-locate on one XCD L2.

__device__ __forceinline__ void gsync_g(int* sc, int gen, int jb){
  __syncthreads();
  if (threadIdx.x == 0){
    int old = __hip_atomic_fetch_add(&sc[(jb & 7)*32], 1, __ATOMIC_RELEASE, __HIP_MEMORY_SCOPE_AGENT);
    bool last = false;
    if (old == gen*8 - 1){
      int old2 = __hip_atomic_fetch_add(&sc[512], 1, __ATOMIC_RELAXED, __HIP_MEMORY_SCOPE_AGENT);
      if (old2 == gen*8 - 1){
        __hip_atomic_store(&sc[544], gen, __ATOMIC_RELEASE, __HIP_MEMORY_SCOPE_AGENT);
        last = true;
      }
    }
    if (!last){
      while (__hip_atomic_load(&sc[544], __ATOMIC_RELAXED, __HIP_MEMORY_SCOPE_AGENT) < gen)
        __builtin_amdgcn_s_sleep(2);
    }
  }
  __syncthreads();
}

// fc over slots: M=16 tile with 8 valid rows (group batches), h from padded LDS stage
__device__ __forceinline__ void fc_run(const KParams& p, const int* sm_dl, const us* hlds,
                                       int b0, int slot, int nslots, int niter,
                                       int la, int lq, int tpred){
  bf16x8 afr[16];
  #pragma unroll
  for (int ks = 0; ks < 16; ks++) afr[ks] = *(const bf16x8*)&hlds[(la & 7)*HS + lq*8 + ks*32];
  for (int it = 0; it < niter; it++){
    int tile = slot + it*nslots;
    if (tile < 625){
      int n0 = tile*16;
      const us* wp = p.Wt + ((size_t)(4608 + n0 + la))*512 + lq*8;
      f32x4 ac = {};
      #pragma unroll
      for (int ks = 0; ks < 16; ks++){
        bf16x8 bB = *(const bf16x8*)(wp + ks*32);
        ac = MFMA(afr[ks], bB, ac);
      }
      if (lq < 2){
        int v = n0 + la;
        float bb = p.fc_b[v];
        #pragma unroll
        for (int r = 0; r < 4; r++){
          int b = b0 + lq*4 + r;
          bool act = tpred < sm_dl[b];
          p.out_preds[((size_t)b*T_ + tpred)*V_ + v] = act ? (ac[r] + bb) : 0.f;
        }
      }
    }
  }
}

__global__ void __launch_bounds__(512, 2) k_loop(KParams p){
  const int tid = threadIdx.x, blk = blockIdx.x;
  const int gb = blk >> 6, jb = blk & 63, b0 = gb*8;  // 4 groups x 64 blocks; XCD = jb%8
  const int wv = tid >> 6, lane = tid & 63, la = lane & 15, lq = lane >> 4;
  int* sc = p.sync + gb*1024;
  __shared__ float sm_att2[512], sm_fw[512], sm_red[16];
  __shared__ float sm_a4f[8*PP];
  __shared__ float gq2[4][2][16][8];
  __shared__ int sm_dl[32];
  __shared__ us sm_h[8*HS];      // coherent-staged h rows (padded, conflict-free)
  __shared__ us sm_awe[8*AS];    // coherent-staged awe / mean (padded, conflict-free)
  int gen = 0;

  if (tid < 32) sm_dl[tid] = p.declen[tid];
  __syncthreads();

  // ===== GP1: mean over p — 32 d/block x 8 b, 2 threads per (d,b) =====
  {
    int part = tid & 1, pair = tid >> 1;
    int d = jb*32 + (pair >> 3), b = b0 + (pair & 7);
    const uint4* rp = (const uint4*)(p.encT + ((size_t)b*D_ + d)*PP);
    int cs = part*13;
    float s = 0.f;
    for (int i = cs; i < cs + 13; i++){
      uint4 u = rp[i];
      s += bf2f(u.x&0xffffu)+bf2f(u.x>>16)+bf2f(u.y&0xffffu)+bf2f(u.y>>16)
         + bf2f(u.z&0xffffu)+bf2f(u.z>>16)+bf2f(u.w&0xffffu)+bf2f(u.w>>16);
    }
    s += __shfl_xor(s, 1);
    float mv = s*(1.f/196.f);
    float ov = __shfl_xor(mv, 16);          // partner: d^1 (tid bit4), same b
    if (part == 0 && !(tid & 16))
      ast((unsigned*)p.mean_bf16 + ((size_t)b*1024 + (d >> 1)), pack2(mv, ov));
  }
  gsync_g(sc, ++gen, jb);
  // ===== GP2: h0/c0 = mean @ Wt3 — 64 tiles over blocks 0..7 x 8 waves =====
  if (jb < 8){
    {
      unsigned* dst = (unsigned*)sm_awe;
      const unsigned* src = (const unsigned*)p.mean_bf16 + (size_t)b0*1024;
      for (int i = tid; i < 8192; i += 512) dst[(i >> 10)*(AS >> 1) + (i & 1023)] = ald(src + i);
    }
    __syncthreads();
    int slot = jb*8 + wv;
    const us* wp = p.Wt3 + ((size_t)(slot*16 + la))*2048 + lq*8;
    const us* ap = sm_awe + (la & 7)*AS + lq*8;
    f32x4 ac0 = {}, ac1 = {};
    for (int ki = 0; ki < 64; ki += 2){
      bf16x8 aA = *(const bf16x8*)(ap + ki*32);
      bf16x8 bB = *(const bf16x8*)(wp + ki*32);
      ac0 = MFMA(aA, bB, ac0);
      bf16x8 aA2 = *(const bf16x8*)(ap + ki*32 + 32);
      bf16x8 bB2 = *(const bf16x8*)(wp + ki*32 + 32);
      ac1 = MFMA(aA2, bB2, ac1);
    }
    f32x4 ac = ac0 + ac1;
    int col = slot*16 + la;
    if (col < 512){
      #pragma unroll
      for (int r = 0; r < 4; r++){
        float v0 = ac[r] + p.init_h_b[col];
        float v1 = __shfl_xor(v0, 1);       // partner col^1, same row
        if (lq < 2 && !(la & 1))
          ast((unsigned*)p.h_bf16 + (((size_t)(b0 + lq*4 + r)*512 + col) >> 1), pack2(v0, v1));
      }
    } else {
      #pragma unroll
      for (int r = 0; r < 4; r++)
        if (lq < 2) astf(&p.c[(size_t)(b0 + lq*4 + r)*512 + col - 512], ac[r] + p.init_c_b[col - 512]);
    }
  }
  gsync_g(sc, ++gen, jb);

  for (int t = 0; t < T_; ++t){
    // ===== stage h (coherent) -> padded LDS (8 rows) =====
    {
      unsigned* dst = (unsigned*)sm_h;
      const unsigned* src = (const unsigned*)p.h_bf16 + (size_t)b0*256;
      for (int i = tid; i < 2048; i += 512) dst[(i >> 8)*(HS >> 1) + (i & 255)] = ald(src + i);
    }
    __syncthreads();
    // ===== G1: s1out = h @ Wt — 288 tiles over 512 wave-slots, <=1 each =====
    {
      int slot = jb*8 + wv;
      if (slot < 288){
        bf16x8 afr[16];
        #pragma unroll
        for (int ks = 0; ks < 16; ks++) afr[ks] = *(const bf16x8*)&sm_h[(la & 7)*HS + lq*8 + ks*32];
        int n0 = slot*16;
        const us* wp = p.Wt + ((size_t)(n0 + la))*512 + lq*8;
        f32x4 ac = {};
        #pragma unroll
        for (int ks = 0; ks < 16; ks++){
          bf16x8 bB = *(const bf16x8*)(wp + ks*32);
          ac = MFMA(afr[ks], bB, ac);
        }
        if (lq < 2){
          #pragma unroll
          for (int r = 0; r < 4; r++) astf(&p.s1out[(size_t)(b0 + lq*4 + r)*4608 + n0 + la], ac[r]);
        }
      }
    }
    gsync_g(sc, ++gen, jb);
    // ===== G2: blocks 0..7 attention softmax (1/XCD) | blocks 8..63 fc preds[t-1] =====
    if (jb < 8){
      int b = b0 + jb;
      for (int cc = tid; cc < 512; cc += 512){
        sm_att2[cc] = aldf(&p.s1out[(size_t)b*4608 + cc]) + p.dec_att_b[cc];
        sm_fw[cc]   = p.full_att_w[cc];
      }
      __syncthreads();
      float ee = -1e30f;
      if (tid < 196){
        const uint4* row = (const uint4*)(p.att1 + ((size_t)(b*196 + tid))*512);
        float s = 0.f;
        #pragma unroll 8
        for (int i = 0; i < 64; i++){
          uint4 u = row[i];
          float4 a0 = *(const float4*)&sm_att2[i*8], a1 = *(const float4*)&sm_att2[i*8+4];
          float4 f0 = *(const float4*)&sm_fw[i*8],   f1 = *(const float4*)&sm_fw[i*8+4];
          s += fmaxf(bf2f(u.x&0xffffu)+a0.x,0.f)*f0.x + fmaxf(bf2f(u.x>>16)+a0.y,0.f)*f0.y
             + fmaxf(bf2f(u.y&0xffffu)+a0.z,0.f)*f0.z + fmaxf(bf2f(u.y>>16)+a0.w,0.f)*f0.w
             + fmaxf(bf2f(u.z&0xffffu)+a1.x,0.f)*f1.x + fmaxf(bf2f(u.z>>16)+a1.y,0.f)*f1.y
             + fmaxf(bf2f(u.w&0xffffu)+a1.z,0.f)*f1.z + fmaxf(bf2f(u.w>>16)+a1.w,0.f)*f1.w;
        }
        ee = s;
      }
      float v = ee;
      #pragma unroll
      for (int off = 32; off; off >>= 1) v = fmaxf(v, __shfl_xor(v, off));
      if (lane == 0) sm_red[wv] = v;
      __syncthreads();
      float m = sm_red[0];
      #pragma unroll
      for (int i = 1; i < 8; i++) m = fmaxf(m, sm_red[i]);
      float ex = (tid < 196) ? __expf(ee - m) : 0.f;
      float sv = ex;
      #pragma unroll
      for (int off = 32; off; off >>= 1) sv += __shfl_xor(sv, off);
      if (lane == 0) sm_red[8 + wv] = sv;
      __syncthreads();
      float ssum = sm_red[8];
      #pragma unroll
      for (int i = 1; i < 8; i++) ssum += sm_red[8 + i];
      if (tid < 196){
        float a = ex/ssum;
        astf(&p.alpha_g[b*PP + tid], a);
        bool act = t < sm_dl[b];
        p.out_alphas[((size_t)b*T_ + t)*P_ + tid] = act ? a : 0.f;
      } else if (tid < PP) astf(&p.alpha_g[b*PP + tid], 0.f);
    } else if (t > 0){
      fc_run(p, sm_dl, sm_h, b0, (jb - 8)*8 + wv, 448, 2, la, lq, t - 1);
    }
    gsync_g(sc, ++gen, jb);
    // ===== G3: awe = gate * (alpha @ enc) — 32 d/block x 8 b, 2 thr/(d,b) =====
    {
      for (int i = tid; i < 8*PP; i += 512) sm_a4f[i] = aldf(&p.alpha_g[b0*PP + i]);
      __syncthreads();
      int part = tid & 1, pair = tid >> 1;
      int d = jb*32 + (pair >> 3), b = b0 + (pair & 7);
      const float* al = sm_a4f + (pair & 7)*PP;
      const uint4* rp = (const uint4*)(p.encT + ((size_t)b*D_ + d)*PP);
      int cs = part*13;
      float acc = 0.f;
      for (int i = cs; i < cs + 13; i++){
        uint4 u = rp[i];
        float4 a0 = *(const float4*)(al + i*8), a1 = *(const float4*)(al + i*8 + 4);
        acc += a0.x*bf2f(u.x&0xffffu) + a0.y*bf2f(u.x>>16)
             + a0.z*bf2f(u.y&0xffffu) + a0.w*bf2f(u.y>>16)
             + a1.x*bf2f(u.z&0xffffu) + a1.y*bf2f(u.z>>16)
             + a1.z*bf2f(u.w&0xffffu) + a1.w*bf2f(u.w>>16);
      }
      acc += __shfl_xor(acc, 1);
      float gate = sigm(aldf(&p.s1out[(size_t)b*4608 + 512 + d]) + p.f_beta_b[d]);
      float wv_ = acc*gate;
      float ov = __shfl_xor(wv_, 16);       // partner: d^1 (tid bit4), same b
      if (part == 0 && !(tid & 16))
        ast((unsigned*)p.awe_bf16 + ((size_t)b*1024 + (d >> 1)), pack2(wv_, ov));
    }
    gsync_g(sc, ++gen, jb);
    // ===== G4: g = gpre + ghh + awe@Wt2 (blocks 0..31: gate x K-half/wave) + LSTM =====
    if (jb < 32){
      {
        unsigned* dst = (unsigned*)sm_awe;
        const unsigned* src = (const unsigned*)p.awe_bf16 + (size_t)b0*1024;
        for (int i = tid; i < 8192; i += 512) dst[(i >> 10)*(AS >> 1) + (i & 1023)] = ald(src + i);
      }
      __syncthreads();
      int q = wv >> 1, kh = wv & 1, hc0 = jb*16;
      const us* wp = p.Wt2 + ((size_t)(q*512 + hc0 + la))*2048 + kh*1024 + lq*8;
      const us* ap = sm_awe + (la & 7)*AS + kh*1024 + lq*8;
      f32x4 ac0 = {}, ac1 = {};
      for (int ki = 0; ki < 32; ki += 2){
        bf16x8 aA = *(const bf16x8*)(ap + ki*32);
        bf16x8 bB = *(const bf16x8*)(wp + ki*32);
        ac0 = MFMA(aA, bB, ac0);
        bf16x8 aA2 = *(const bf16x8*)(ap + ki*32 + 32);
        bf16x8 bB2 = *(const bf16x8*)(wp + ki*32 + 32);
        ac1 = MFMA(aA2, bB2, ac1);
      }
      f32x4 ac = ac0 + ac1;
      if (lq < 2){
        #pragma unroll
        for (int r = 0; r < 4; r++) gq2[q][kh][la][lq*4 + r] = ac[r];
      }
      __syncthreads();
      if (tid < 128){
        int hc = hc0 + (tid & 15), r = tid >> 4;   // r = 0..7
        int b = b0 + r;
        float gv[4];
        #pragma unroll
        for (int qq = 0; qq < 4; qq++)
          gv[qq] = gq2[qq][0][tid & 15][r] + gq2[qq][1][tid & 15][r]
                 + aldf(&p.s1out[(size_t)b*4608 + 2560 + qq*512 + hc])
                 + p.gpre[((size_t)t*32 + b)*2048 + qq*512 + hc];
        float cold = aldf(&p.c[(size_t)b*512 + hc]);
        float cn = sigm(gv[1])*cold + sigm(gv[0])*tanh_f(gv[2]);
        float hn = sigm(gv[3])*tanh_f(cn);
        float hv1 = __shfl_xor(hn, 1);      // partner hc^1, same b
        if (t < sm_dl[b]){
          astf(&p.c[(size_t)b*512 + hc], cn);
          if (!(tid & 1))
            ast((unsigned*)p.h_bf16 + (((size_t)b*512 + hc) >> 1), pack2(hn, hv1));
        }
      }
    }
    gsync_g(sc, ++gen, jb);
  }
  // ===== epilogue: preds[T-1] (all 64 blocks x 8 waves per group) =====
  {
    unsigned* dst = (unsigned*)sm_h;
    const unsigned* src = (const unsigned*)p.h_bf16 + (size_t)b0*256;
    for (int i = tid; i < 2048; i += 512) dst[(i >> 8)*(HS >> 1) + (i & 255)] = ald(src + i);
  }
  __syncthreads();
  fc_run(p, sm_dl, sm_h, b0, jb*8 + wv, 512, 2, la, lq, T_ - 1);
}

// ---------------- host launcher ----------------

extern "C" void kernel_launch(void* const* d_in, const int* in_sizes, int n_in,
                              void* d_out, int out_size, void* d_ws, size_t ws_size,
                              hipStream_t stream){
  (void)in_sizes; (void)n_in; (void)out_size; (void)ws_size;
  KParams p;
  p.encoder_out = (const float*)d_in[0];
  p.captions    = (const int*)d_in[1];
  p.cap_lens    = (const int*)d_in[2];
  p.enc_att_w   = (const float*)d_in[3];  p.enc_att_b = (const float*)d_in[4];
  p.dec_att_w   = (const float*)d_in[5];  p.dec_att_b = (const float*)d_in[6];
  p.full_att_w  = (const float*)d_in[7];  p.full_att_b = (const float*)d_in[8];
  p.emb         = (const float*)d_in[9];
  p.init_h_w    = (const float*)d_in[10]; p.init_h_b = (const float*)d_in[11];
  p.init_c_w    = (const float*)d_in[12]; p.init_c_b = (const float*)d_in[13];
  p.f_beta_w    = (const float*)d_in[14]; p.f_beta_b = (const float*)d_in[15];
  p.lstm_w_ih   = (const float*)d_in[16]; p.lstm_w_hh = (const float*)d_in[17]; p.lstm_b = (const float*)d_in[18];
  p.fc_w        = (const float*)d_in[19]; p.fc_b = (const float*)d_in[20];

  float* out = (float*)d_out;
  p.out_preds   = out;
  p.out_caps    = out + 6400000;
  p.out_declens = out + 6400672;
  p.out_alphas  = out + 6400704;
  p.out_sortind = out + 6526144;

  char* w = (char*)d_ws; size_t off = 0;
  auto alloc = [&](size_t bytes)->char*{ char* r = w + off; off = (off + bytes + 255) & ~(size_t)255; return r; };
  p.sort_ind  = (int*)alloc(128);
  p.declen    = (int*)alloc(128);
  p.caps_s    = (int*)alloc(2688);
  p.h_bf16    = (us*)alloc(32768);
  p.c         = (float*)alloc(65536);
  p.mean_bf16 = (us*)alloc(131072);
  p.waw_bf16  = (us*)alloc(2097152);
  p.wihE_bf16 = (us*)alloc(2097152);
  p.embs_bf16 = (us*)alloc(655360);
  p.att1      = (us*)alloc(6422528);     // [6272][512] bf16
  p.Wt        = (us*)alloc(14958592);    // [14608][512] bf16
  p.Wt2       = (us*)alloc(8388608);     // [2048][2048] bf16
  p.Wt3       = (us*)alloc(4194304);     // [1024][2048] bf16
  p.encT      = (us*)alloc(27262976);    // [32][2048][208] bf16
  p.gpre      = (float*)alloc(5242880);  // [20][32][2048]
  p.s1out     = (float*)alloc(589824);   // [32][4608]
  p.alpha_g   = (float*)alloc(26624);    // [32][208]
  p.awe_bf16  = (us*)alloc(131072);      // [32][2048]
  p.sync      = (int*)alloc(32768);      // 4 groups x 1024 ints

  hipMemsetAsync(p.sync, 0, 32768, stream);
  hipLaunchKernelGGL(k_meta,  dim3(1),    dim3(64),  0, stream, p);
  hipLaunchKernelGGL(k_prep1, dim3(832),  dim3(256), 0, stream, p);
  hipLaunchKernelGGL(k_big,   dim3(7740), dim3(256), 0, stream, p);
  void* args[] = { (void*)&p };
  hipLaunchCooperativeKernel((void*)k_loop, dim3(256), dim3(512), args, 0, stream);
}